// Round 1
// baseline (997.345 us; speedup 1.0000x reference)
//
#include <hip/hip_runtime.h>

#define N_NODES 100000
#define N_EDGES 1600000
#define HID 128
#define N_GRAPHS 256

// ---------------- zero ----------------
__global__ void zero_kernel(int* __restrict__ p, int n) {
    int i = blockIdx.x * blockDim.x + threadIdx.x;
    if (i < n) p[i] = 0;
}

// ---------------- degree ----------------
__global__ void deg_kernel(const int* __restrict__ dst, int* __restrict__ degi) {
    int e = blockIdx.x * blockDim.x + threadIdx.x;
    if (e < N_EDGES) atomicAdd(&degi[dst[e]], 1);
}

__global__ void dis_kernel(const int* __restrict__ degi, float* __restrict__ dis) {
    int i = blockIdx.x * blockDim.x + threadIdx.x;
    if (i < N_NODES) dis[i] = rsqrtf(1.0f + (float)degi[i]);
}

// ---------------- scan (CSR rowptr) ----------------
__global__ __launch_bounds__(1024) void scan1(const int* __restrict__ degi,
                                              int* __restrict__ incl,
                                              int* __restrict__ bsum) {
    __shared__ int s[1024];
    int i = blockIdx.x * 1024 + threadIdx.x;
    int v = (i < N_NODES) ? degi[i] : 0;
    s[threadIdx.x] = v;
    __syncthreads();
    for (int off = 1; off < 1024; off <<= 1) {
        int t = (threadIdx.x >= off) ? s[threadIdx.x - off] : 0;
        __syncthreads();
        s[threadIdx.x] += t;
        __syncthreads();
    }
    if (i < N_NODES) incl[i] = s[threadIdx.x];
    if (threadIdx.x == 1023) bsum[blockIdx.x] = s[1023];
}

__global__ void scan2(int* __restrict__ bsum, int nb) {
    __shared__ int s[128];
    int t = threadIdx.x;
    int v = (t < nb) ? bsum[t] : 0;
    s[t] = v;
    __syncthreads();
    for (int off = 1; off < 128; off <<= 1) {
        int a = (t >= off) ? s[t - off] : 0;
        __syncthreads();
        s[t] += a;
        __syncthreads();
    }
    if (t < nb) bsum[t] = s[t] - v;  // exclusive base per block
}

__global__ void rowptr_kernel(const int* __restrict__ incl, const int* __restrict__ degi,
                              const int* __restrict__ bsum, int* __restrict__ rowptr) {
    int i = blockIdx.x * blockDim.x + threadIdx.x;
    if (i < N_NODES) rowptr[i] = incl[i] - degi[i] + bsum[i >> 10];
}

__global__ void scatter_kernel(const int* __restrict__ src, const int* __restrict__ dst,
                               const int* __restrict__ rowptr, int* __restrict__ fill,
                               int* __restrict__ csr) {
    int e = blockIdx.x * blockDim.x + threadIdx.x;
    if (e < N_EDGES) {
        int d = dst[e];
        int pos = rowptr[d] + atomicAdd(&fill[d], 1);
        csr[pos] = src[e];
    }
}

// ---------------- GEMM: Y[M,128] = X[M,128] @ W[128,128] (fp32) ----------------
// Block: 256 threads, 128 rows/block. Thread: 2 rows x 32 cols.
__global__ __launch_bounds__(256) void gemm_kernel(const float* __restrict__ X,
                                                   const float* __restrict__ W,
                                                   float* __restrict__ Y, int M) {
    __shared__ float Wl[128 * 128];
    {
        const float4* W4 = (const float4*)W;
        float4* Wl4 = (float4*)Wl;
        for (int t = threadIdx.x; t < 128 * 128 / 4; t += 256) Wl4[t] = W4[t];
    }
    __syncthreads();

    int tg = threadIdx.x >> 2;   // 0..63
    int q  = threadIdx.x & 3;    // 0..3 -> col quarter
    int r0 = blockIdx.x * 128 + tg * 2;
    if (r0 >= M) return;
    int r1 = r0 + 1;

    float acc0[32], acc1[32];
#pragma unroll
    for (int j = 0; j < 32; j++) { acc0[j] = 0.f; acc1[j] = 0.f; }

    const float4* x0 = (const float4*)(X + (size_t)r0 * 128);
    const float4* x1 = (const float4*)(X + (size_t)r1 * 128);

    for (int k4 = 0; k4 < 32; k4++) {
        float a0[4], a1[4];
        *(float4*)a0 = x0[k4];
        *(float4*)a1 = x1[k4];
#pragma unroll
        for (int kk = 0; kk < 4; kk++) {
            const float4* wr = (const float4*)(&Wl[(k4 * 4 + kk) * 128 + q * 32]);
#pragma unroll
            for (int j4 = 0; j4 < 8; j4++) {
                float4 w = wr[j4];
                acc0[j4 * 4 + 0] += a0[kk] * w.x;
                acc0[j4 * 4 + 1] += a0[kk] * w.y;
                acc0[j4 * 4 + 2] += a0[kk] * w.z;
                acc0[j4 * 4 + 3] += a0[kk] * w.w;
                acc1[j4 * 4 + 0] += a1[kk] * w.x;
                acc1[j4 * 4 + 1] += a1[kk] * w.y;
                acc1[j4 * 4 + 2] += a1[kk] * w.z;
                acc1[j4 * 4 + 3] += a1[kk] * w.w;
            }
        }
    }

    float4* y0 = (float4*)(Y + (size_t)r0 * 128 + q * 32);
    float4* y1 = (float4*)(Y + (size_t)r1 * 128 + q * 32);
#pragma unroll
    for (int j4 = 0; j4 < 8; j4++) {
        y0[j4] = make_float4(acc0[j4 * 4], acc0[j4 * 4 + 1], acc0[j4 * 4 + 2], acc0[j4 * 4 + 3]);
        y1[j4] = make_float4(acc1[j4 * 4], acc1[j4 * 4 + 1], acc1[j4 * 4 + 2], acc1[j4 * 4 + 3]);
    }
}

// ---------------- aggregation: one wave per node ----------------
__global__ __launch_bounds__(256) void aggregate_kernel(
    const float* __restrict__ T, const int* __restrict__ csr,
    const int* __restrict__ rowptr, const int* __restrict__ degi,
    const float* __restrict__ dis, const float* __restrict__ bias,
    float* __restrict__ H) {
    int node = blockIdx.x * 4 + (threadIdx.x >> 6);
    int lane = threadIdx.x & 63;
    if (node >= N_NODES) return;

    float di = dis[node];
    int start = rowptr[node];
    int cnt = degi[node];
    const float2* T2 = (const float2*)T;

    float2 acc = make_float2(0.f, 0.f);
    int j = 0;
    for (; j + 1 < cnt; j += 2) {
        int s0 = csr[start + j];
        int s1 = csr[start + j + 1];
        float c0 = di * dis[s0];
        float c1 = di * dis[s1];
        float2 v0 = T2[(size_t)s0 * 64 + lane];
        float2 v1 = T2[(size_t)s1 * 64 + lane];
        acc.x += c0 * v0.x + c1 * v1.x;
        acc.y += c0 * v0.y + c1 * v1.y;
    }
    if (j < cnt) {
        int s0 = csr[start + j];
        float c0 = di * dis[s0];
        float2 v0 = T2[(size_t)s0 * 64 + lane];
        acc.x += c0 * v0.x;
        acc.y += c0 * v0.y;
    }

    // self-loop: h[i] / deg[i] = h[i] * dis[i]^2
    float invdeg = di * di;
    float2 self = T2[(size_t)node * 64 + lane];
    acc.x += invdeg * self.x;
    acc.y += invdeg * self.y;

    float2 bb = ((const float2*)bias)[lane];
    acc.x = fmaxf(acc.x + bb.x, 0.f);
    acc.y = fmaxf(acc.y + bb.y, 0.f);

    ((float2*)H)[(size_t)node * 64 + lane] = acc;
}

// ---------------- pool + FC ----------------
__global__ __launch_bounds__(256) void pool_kernel(const float* __restrict__ H,
                                                   const int* __restrict__ batch,
                                                   const float* __restrict__ Wfc,
                                                   float* __restrict__ gsum,
                                                   int* __restrict__ gcnt) {
    int node = blockIdx.x * 4 + (threadIdx.x >> 6);
    int lane = threadIdx.x & 63;
    if (node >= N_NODES) return;
    const float2* H2 = (const float2*)H;
    const float2* W2 = (const float2*)Wfc;
    float2 h = H2[(size_t)node * 64 + lane];
    float2 w = W2[lane];
    float d = h.x * w.x + h.y * w.y;
#pragma unroll
    for (int off = 32; off > 0; off >>= 1) d += __shfl_down(d, off);
    if (lane == 0) {
        int g = batch[node];
        atomicAdd(&gsum[g], d);
        atomicAdd(&gcnt[g], 1);
    }
}

__global__ void finalize_kernel(const float* __restrict__ gsum, const int* __restrict__ gcnt,
                                const float* __restrict__ bfc, float* __restrict__ out) {
    int g = blockIdx.x * blockDim.x + threadIdx.x;
    if (g < N_GRAPHS) out[g] = gsum[g] / fmaxf((float)gcnt[g], 1.0f) + bfc[0];
}

// ---------------- launcher ----------------
extern "C" void kernel_launch(void* const* d_in, const int* in_sizes, int n_in,
                              void* d_out, int out_size, void* d_ws, size_t ws_size,
                              hipStream_t stream) {
    const float* x    = (const float*)d_in[0];
    const int*   eidx = (const int*)d_in[1];   // [2, E]: first E = src, next E = dst
    const int*   batch= (const int*)d_in[2];
    const float* W1   = (const float*)d_in[3];
    const float* b1   = (const float*)d_in[4];
    const float* W2   = (const float*)d_in[5];
    const float* b2   = (const float*)d_in[6];
    const float* Wfc  = (const float*)d_in[7];
    const float* bfc  = (const float*)d_in[8];
    float* out = (float*)d_out;

    const int* src = eidx;
    const int* dst = eidx + N_EDGES;

    size_t off = 0;
    char* base = (char*)d_ws;
    auto alloc = [&](size_t bytes) -> void* {
        void* p = base + off;
        off += (bytes + 255) & ~(size_t)255;
        return p;
    };
    // zeroed region first (contiguous): degi, fill, gsum, gcnt
    int*   degi   = (int*)alloc(N_NODES * 4);
    int*   fill   = (int*)alloc(N_NODES * 4);
    float* gsum   = (float*)alloc(N_GRAPHS * 4);
    int*   gcnt   = (int*)alloc(N_GRAPHS * 4);
    size_t zero_bytes = off;  // everything from base up to here gets zeroed
    float* A      = (float*)alloc((size_t)N_NODES * HID * 4);
    float* B      = (float*)alloc((size_t)N_NODES * HID * 4);
    int*   incl   = (int*)alloc(N_NODES * 4);
    int*   rowptr = (int*)alloc(N_NODES * 4);
    float* dis    = (float*)alloc(N_NODES * 4);
    int*   csr    = (int*)alloc(N_EDGES * 4);
    int*   bsum   = (int*)alloc(1024);

    int zn = (int)(zero_bytes / 4);
    zero_kernel<<<(zn + 255) / 256, 256, 0, stream>>>((int*)base, zn);

    // degree + normalization
    deg_kernel<<<(N_EDGES + 255) / 256, 256, 0, stream>>>(dst, degi);
    dis_kernel<<<(N_NODES + 255) / 256, 256, 0, stream>>>(degi, dis);

    // CSR build
    int nb = (N_NODES + 1023) / 1024;  // 98
    scan1<<<nb, 1024, 0, stream>>>(degi, incl, bsum);
    scan2<<<1, 128, 0, stream>>>(bsum, nb);
    rowptr_kernel<<<(N_NODES + 255) / 256, 256, 0, stream>>>(incl, degi, bsum, rowptr);
    scatter_kernel<<<(N_EDGES + 255) / 256, 256, 0, stream>>>(src, dst, rowptr, fill, csr);

    int gemm_grid = (N_NODES + 127) / 128;
    int agg_grid  = (N_NODES + 3) / 4;

    // layer 1
    gemm_kernel<<<gemm_grid, 256, 0, stream>>>(x, W1, A, N_NODES);
    aggregate_kernel<<<agg_grid, 256, 0, stream>>>(A, csr, rowptr, degi, dis, b1, B);
    // layer 2
    gemm_kernel<<<gemm_grid, 256, 0, stream>>>(B, W2, A, N_NODES);
    aggregate_kernel<<<agg_grid, 256, 0, stream>>>(A, csr, rowptr, degi, dis, b2, B);

    // pool + fc
    pool_kernel<<<agg_grid, 256, 0, stream>>>(B, batch, Wfc, gsum, gcnt);
    finalize_kernel<<<1, 256, 0, stream>>>(gsum, gcnt, bfc, out);
}

// Round 2
// 650.044 us; speedup vs baseline: 1.5343x; 1.5343x over previous
//
#include <hip/hip_runtime.h>

#define N_NODES 100000
#define N_EDGES 1600000
#define HID 128
#define N_GRAPHS 256
#define POOL_BLOCKS 512

// ---------------- zero ----------------
__global__ void zero_kernel(int* __restrict__ p, int n) {
    int i = blockIdx.x * blockDim.x + threadIdx.x;
    if (i < n) p[i] = 0;
}

// ---------------- degree ----------------
__global__ void deg_kernel(const int* __restrict__ dst, int* __restrict__ degi) {
    int e = blockIdx.x * blockDim.x + threadIdx.x;
    if (e < N_EDGES) atomicAdd(&degi[dst[e]], 1);
}

__global__ void dis_kernel(const int* __restrict__ degi, float* __restrict__ dis) {
    int i = blockIdx.x * blockDim.x + threadIdx.x;
    if (i < N_NODES) dis[i] = rsqrtf(1.0f + (float)degi[i]);
}

// ---------------- scan (CSR rowptr) ----------------
__global__ __launch_bounds__(1024) void scan1(const int* __restrict__ degi,
                                              int* __restrict__ incl,
                                              int* __restrict__ bsum) {
    __shared__ int s[1024];
    int i = blockIdx.x * 1024 + threadIdx.x;
    int v = (i < N_NODES) ? degi[i] : 0;
    s[threadIdx.x] = v;
    __syncthreads();
    for (int off = 1; off < 1024; off <<= 1) {
        int t = (threadIdx.x >= off) ? s[threadIdx.x - off] : 0;
        __syncthreads();
        s[threadIdx.x] += t;
        __syncthreads();
    }
    if (i < N_NODES) incl[i] = s[threadIdx.x];
    if (threadIdx.x == 1023) bsum[blockIdx.x] = s[1023];
}

__global__ void scan2(int* __restrict__ bsum, int nb) {
    __shared__ int s[128];
    int t = threadIdx.x;
    int v = (t < nb) ? bsum[t] : 0;
    s[t] = v;
    __syncthreads();
    for (int off = 1; off < 128; off <<= 1) {
        int a = (t >= off) ? s[t - off] : 0;
        __syncthreads();
        s[t] += a;
        __syncthreads();
    }
    if (t < nb) bsum[t] = s[t] - v;  // exclusive base per block
}

__global__ void rowptr_kernel(const int* __restrict__ incl, const int* __restrict__ degi,
                              const int* __restrict__ bsum, int* __restrict__ rowptr) {
    int i = blockIdx.x * blockDim.x + threadIdx.x;
    if (i < N_NODES) rowptr[i] = incl[i] - degi[i] + bsum[i >> 10];
}

__global__ void scatter_kernel(const int* __restrict__ src, const int* __restrict__ dst,
                               const int* __restrict__ rowptr, int* __restrict__ fill,
                               int* __restrict__ csr) {
    int e = blockIdx.x * blockDim.x + threadIdx.x;
    if (e < N_EDGES) {
        int d = dst[e];
        int pos = rowptr[d] + atomicAdd(&fill[d], 1);
        csr[pos] = src[e];
    }
}

// ---------------- GEMM: Y[M,128] = X[M,128] @ W[128,128] (fp32) ----------------
__global__ __launch_bounds__(256) void gemm_kernel(const float* __restrict__ X,
                                                   const float* __restrict__ W,
                                                   float* __restrict__ Y, int M) {
    __shared__ float Wl[128 * 128];
    {
        const float4* W4 = (const float4*)W;
        float4* Wl4 = (float4*)Wl;
        for (int t = threadIdx.x; t < 128 * 128 / 4; t += 256) Wl4[t] = W4[t];
    }
    __syncthreads();

    int tg = threadIdx.x >> 2;   // 0..63
    int q  = threadIdx.x & 3;    // 0..3 -> col quarter
    int r0 = blockIdx.x * 128 + tg * 2;
    if (r0 >= M) return;
    int r1 = r0 + 1;

    float acc0[32], acc1[32];
#pragma unroll
    for (int j = 0; j < 32; j++) { acc0[j] = 0.f; acc1[j] = 0.f; }

    const float4* x0 = (const float4*)(X + (size_t)r0 * 128);
    const float4* x1 = (const float4*)(X + (size_t)r1 * 128);

    for (int k4 = 0; k4 < 32; k4++) {
        float a0[4], a1[4];
        *(float4*)a0 = x0[k4];
        *(float4*)a1 = x1[k4];
#pragma unroll
        for (int kk = 0; kk < 4; kk++) {
            const float4* wr = (const float4*)(&Wl[(k4 * 4 + kk) * 128 + q * 32]);
#pragma unroll
            for (int j4 = 0; j4 < 8; j4++) {
                float4 w = wr[j4];
                acc0[j4 * 4 + 0] += a0[kk] * w.x;
                acc0[j4 * 4 + 1] += a0[kk] * w.y;
                acc0[j4 * 4 + 2] += a0[kk] * w.z;
                acc0[j4 * 4 + 3] += a0[kk] * w.w;
                acc1[j4 * 4 + 0] += a1[kk] * w.x;
                acc1[j4 * 4 + 1] += a1[kk] * w.y;
                acc1[j4 * 4 + 2] += a1[kk] * w.z;
                acc1[j4 * 4 + 3] += a1[kk] * w.w;
            }
        }
    }

    float4* y0 = (float4*)(Y + (size_t)r0 * 128 + q * 32);
    float4* y1 = (float4*)(Y + (size_t)r1 * 128 + q * 32);
#pragma unroll
    for (int j4 = 0; j4 < 8; j4++) {
        y0[j4] = make_float4(acc0[j4 * 4], acc0[j4 * 4 + 1], acc0[j4 * 4 + 2], acc0[j4 * 4 + 3]);
        y1[j4] = make_float4(acc1[j4 * 4], acc1[j4 * 4 + 1], acc1[j4 * 4 + 2], acc1[j4 * 4 + 3]);
    }
}

// ---------------- aggregation: one wave per node ----------------
__global__ __launch_bounds__(256) void aggregate_kernel(
    const float* __restrict__ T, const int* __restrict__ csr,
    const int* __restrict__ rowptr, const int* __restrict__ degi,
    const float* __restrict__ dis, const float* __restrict__ bias,
    float* __restrict__ H) {
    int node = blockIdx.x * 4 + (threadIdx.x >> 6);
    int lane = threadIdx.x & 63;
    if (node >= N_NODES) return;

    float di = dis[node];
    int start = rowptr[node];
    int cnt = degi[node];
    const float2* T2 = (const float2*)T;

    float2 acc = make_float2(0.f, 0.f);
    int j = 0;
    for (; j + 1 < cnt; j += 2) {
        int s0 = csr[start + j];
        int s1 = csr[start + j + 1];
        float c0 = di * dis[s0];
        float c1 = di * dis[s1];
        float2 v0 = T2[(size_t)s0 * 64 + lane];
        float2 v1 = T2[(size_t)s1 * 64 + lane];
        acc.x += c0 * v0.x + c1 * v1.x;
        acc.y += c0 * v0.y + c1 * v1.y;
    }
    if (j < cnt) {
        int s0 = csr[start + j];
        float c0 = di * dis[s0];
        float2 v0 = T2[(size_t)s0 * 64 + lane];
        acc.x += c0 * v0.x;
        acc.y += c0 * v0.y;
    }

    float invdeg = di * di;
    float2 self = T2[(size_t)node * 64 + lane];
    acc.x += invdeg * self.x;
    acc.y += invdeg * self.y;

    float2 bb = ((const float2*)bias)[lane];
    acc.x = fmaxf(acc.x + bb.x, 0.f);
    acc.y = fmaxf(acc.y + bb.y, 0.f);

    ((float2*)H)[(size_t)node * 64 + lane] = acc;
}

// ---------------- pool: chunked per-wave run-accumulation ----------------
// batch is SORTED -> accumulate per-lane feature sums across a graph-run,
// dot with Wfc once per run, one atomic per (wave, run). ~2.5K atomics total.
__global__ __launch_bounds__(256) void pool_kernel(const float* __restrict__ H,
                                                   const int* __restrict__ batch,
                                                   const float* __restrict__ Wfc,
                                                   float* __restrict__ gsum) {
    int wave = threadIdx.x >> 6;
    int lane = threadIdx.x & 63;
    int wid = blockIdx.x * 4 + wave;                 // 0..POOL_BLOCKS*4-1
    const int nwaves = POOL_BLOCKS * 4;
    const int per = (N_NODES + nwaves - 1) / nwaves; // contiguous chunk per wave
    int start = wid * per;
    int end = min(start + per, N_NODES);
    if (start >= end) return;

    const float2* H2 = (const float2*)H;
    float2 w = ((const float2*)Wfc)[lane];
    float2 acc = make_float2(0.f, 0.f);
    int gcur = batch[start];

    for (int node = start; node < end; ++node) {
        int g = batch[node];
        if (g != gcur) {
            float d = acc.x * w.x + acc.y * w.y;
#pragma unroll
            for (int off = 32; off > 0; off >>= 1) d += __shfl_down(d, off);
            if (lane == 0) atomicAdd(&gsum[gcur], d);
            acc = make_float2(0.f, 0.f);
            gcur = g;
        }
        float2 h = H2[(size_t)node * 64 + lane];
        acc.x += h.x;
        acc.y += h.y;
    }
    float d = acc.x * w.x + acc.y * w.y;
#pragma unroll
    for (int off = 32; off > 0; off >>= 1) d += __shfl_down(d, off);
    if (lane == 0) atomicAdd(&gsum[gcur], d);
}

// ---------------- finalize: counts via binary search on sorted batch ----------------
__global__ void finalize_kernel(const float* __restrict__ gsum, const int* __restrict__ batch,
                                const float* __restrict__ bfc, float* __restrict__ out) {
    int g = threadIdx.x;
    if (g >= N_GRAPHS) return;
    auto lb = [&](int key) {
        int lo = 0, hi = N_NODES;
        while (lo < hi) {
            int mid = (lo + hi) >> 1;
            if (batch[mid] < key) lo = mid + 1; else hi = mid;
        }
        return lo;
    };
    int a = lb(g), b = lb(g + 1);
    float cnt = (float)(b - a);
    out[g] = gsum[g] / fmaxf(cnt, 1.0f) + bfc[0];
}

// ---------------- launcher ----------------
extern "C" void kernel_launch(void* const* d_in, const int* in_sizes, int n_in,
                              void* d_out, int out_size, void* d_ws, size_t ws_size,
                              hipStream_t stream) {
    const float* x    = (const float*)d_in[0];
    const int*   eidx = (const int*)d_in[1];   // [2, E]: first E = src, next E = dst
    const int*   batch= (const int*)d_in[2];
    const float* W1   = (const float*)d_in[3];
    const float* b1   = (const float*)d_in[4];
    const float* W2   = (const float*)d_in[5];
    const float* b2   = (const float*)d_in[6];
    const float* Wfc  = (const float*)d_in[7];
    const float* bfc  = (const float*)d_in[8];
    float* out = (float*)d_out;

    const int* src = eidx;
    const int* dst = eidx + N_EDGES;

    size_t off = 0;
    char* base = (char*)d_ws;
    auto alloc = [&](size_t bytes) -> void* {
        void* p = base + off;
        off += (bytes + 255) & ~(size_t)255;
        return p;
    };
    // zeroed region first (contiguous): degi, fill, gsum
    int*   degi   = (int*)alloc(N_NODES * 4);
    int*   fill   = (int*)alloc(N_NODES * 4);
    float* gsum   = (float*)alloc(N_GRAPHS * 4);
    size_t zero_bytes = off;
    float* A      = (float*)alloc((size_t)N_NODES * HID * 4);
    float* B      = (float*)alloc((size_t)N_NODES * HID * 4);
    int*   incl   = (int*)alloc(N_NODES * 4);
    int*   rowptr = (int*)alloc(N_NODES * 4);
    float* dis    = (float*)alloc(N_NODES * 4);
    int*   csr    = (int*)alloc(N_EDGES * 4);
    int*   bsum   = (int*)alloc(1024);

    int zn = (int)(zero_bytes / 4);
    zero_kernel<<<(zn + 255) / 256, 256, 0, stream>>>((int*)base, zn);

    // degree + normalization
    deg_kernel<<<(N_EDGES + 255) / 256, 256, 0, stream>>>(dst, degi);
    dis_kernel<<<(N_NODES + 255) / 256, 256, 0, stream>>>(degi, dis);

    // CSR build
    int nb = (N_NODES + 1023) / 1024;  // 98
    scan1<<<nb, 1024, 0, stream>>>(degi, incl, bsum);
    scan2<<<1, 128, 0, stream>>>(bsum, nb);
    rowptr_kernel<<<(N_NODES + 255) / 256, 256, 0, stream>>>(incl, degi, bsum, rowptr);
    scatter_kernel<<<(N_EDGES + 255) / 256, 256, 0, stream>>>(src, dst, rowptr, fill, csr);

    int gemm_grid = (N_NODES + 127) / 128;
    int agg_grid  = (N_NODES + 3) / 4;

    // layer 1
    gemm_kernel<<<gemm_grid, 256, 0, stream>>>(x, W1, A, N_NODES);
    aggregate_kernel<<<agg_grid, 256, 0, stream>>>(A, csr, rowptr, degi, dis, b1, B);
    // layer 2
    gemm_kernel<<<gemm_grid, 256, 0, stream>>>(B, W2, A, N_NODES);
    aggregate_kernel<<<agg_grid, 256, 0, stream>>>(A, csr, rowptr, degi, dis, b2, B);

    // pool + fc
    pool_kernel<<<POOL_BLOCKS, 256, 0, stream>>>(B, batch, Wfc, gsum);
    finalize_kernel<<<1, 256, 0, stream>>>(gsum, batch, bfc, out);
}

// Round 3
// 505.402 us; speedup vs baseline: 1.9734x; 1.2862x over previous
//
#include <hip/hip_runtime.h>

#define N_NODES 100000
#define N_EDGES 1600000
#define HID 128
#define N_GRAPHS 256
#define POOL_BLOCKS 512

typedef unsigned int uint;
typedef unsigned short ushort;

__device__ __forceinline__ float bf2f(ushort u) {
    return __uint_as_float(((uint)u) << 16);
}
__device__ __forceinline__ ushort f2bf(float f) {
    uint u = __float_as_uint(f);
    u += 0x7FFFu + ((u >> 16) & 1u);   // round-to-nearest-even
    return (ushort)(u >> 16);
}
__device__ __forceinline__ void unpack8(uint4 v, float* o) {
    o[0] = bf2f((ushort)(v.x & 0xFFFF)); o[1] = bf2f((ushort)(v.x >> 16));
    o[2] = bf2f((ushort)(v.y & 0xFFFF)); o[3] = bf2f((ushort)(v.y >> 16));
    o[4] = bf2f((ushort)(v.z & 0xFFFF)); o[5] = bf2f((ushort)(v.z >> 16));
    o[6] = bf2f((ushort)(v.w & 0xFFFF)); o[7] = bf2f((ushort)(v.w >> 16));
}
__device__ __forceinline__ uint4 pack8(const float* r) {
    uint4 o;
    o.x = (uint)f2bf(r[0]) | ((uint)f2bf(r[1]) << 16);
    o.y = (uint)f2bf(r[2]) | ((uint)f2bf(r[3]) << 16);
    o.z = (uint)f2bf(r[4]) | ((uint)f2bf(r[5]) << 16);
    o.w = (uint)f2bf(r[6]) | ((uint)f2bf(r[7]) << 16);
    return o;
}

// ---------------- zero ----------------
__global__ void zero_kernel(int* __restrict__ p, int n) {
    int i = blockIdx.x * blockDim.x + threadIdx.x;
    if (i < n) p[i] = 0;
}

// ---------------- degree ----------------
__global__ void deg_kernel(const int* __restrict__ dst, int* __restrict__ degi) {
    int e = blockIdx.x * blockDim.x + threadIdx.x;
    if (e < N_EDGES) atomicAdd(&degi[dst[e]], 1);
}

__global__ void dis_kernel(const int* __restrict__ degi, float* __restrict__ dis) {
    int i = blockIdx.x * blockDim.x + threadIdx.x;
    if (i < N_NODES) dis[i] = rsqrtf(1.0f + (float)degi[i]);
}

// ---------------- scan (CSR rowptr) ----------------
__global__ __launch_bounds__(1024) void scan1(const int* __restrict__ degi,
                                              int* __restrict__ incl,
                                              int* __restrict__ bsum) {
    __shared__ int s[1024];
    int i = blockIdx.x * 1024 + threadIdx.x;
    int v = (i < N_NODES) ? degi[i] : 0;
    s[threadIdx.x] = v;
    __syncthreads();
    for (int off = 1; off < 1024; off <<= 1) {
        int t = (threadIdx.x >= off) ? s[threadIdx.x - off] : 0;
        __syncthreads();
        s[threadIdx.x] += t;
        __syncthreads();
    }
    if (i < N_NODES) incl[i] = s[threadIdx.x];
    if (threadIdx.x == 1023) bsum[blockIdx.x] = s[1023];
}

__global__ void scan2(int* __restrict__ bsum, int nb) {
    __shared__ int s[128];
    int t = threadIdx.x;
    int v = (t < nb) ? bsum[t] : 0;
    s[t] = v;
    __syncthreads();
    for (int off = 1; off < 128; off <<= 1) {
        int a = (t >= off) ? s[t - off] : 0;
        __syncthreads();
        s[t] += a;
        __syncthreads();
    }
    if (t < nb) bsum[t] = s[t] - v;  // exclusive base per block
}

__global__ void rowptr_kernel(const int* __restrict__ incl, const int* __restrict__ degi,
                              const int* __restrict__ bsum, int* __restrict__ rowptr) {
    int i = blockIdx.x * blockDim.x + threadIdx.x;
    if (i < N_NODES) rowptr[i] = incl[i] - degi[i] + bsum[i >> 10];
}

__global__ void scatter_kernel(const int* __restrict__ src, const int* __restrict__ dst,
                               const int* __restrict__ rowptr, int* __restrict__ fill,
                               int* __restrict__ csr) {
    int e = blockIdx.x * blockDim.x + threadIdx.x;
    if (e < N_EDGES) {
        int d = dst[e];
        int pos = rowptr[d] + atomicAdd(&fill[d], 1);
        csr[pos] = src[e];
    }
}

// ---------------- GEMM (fp32 input): Y_bf16[M,128] = X_f32[M,128] @ W[128,128] ----------------
__global__ __launch_bounds__(256) void gemm_f32in_kernel(const float* __restrict__ X,
                                                         const float* __restrict__ W,
                                                         ushort* __restrict__ Y, int M) {
    __shared__ float Wl[128 * 128];
    {
        const float4* W4 = (const float4*)W;
        float4* Wl4 = (float4*)Wl;
        for (int t = threadIdx.x; t < 128 * 128 / 4; t += 256) Wl4[t] = W4[t];
    }
    __syncthreads();

    int tg = threadIdx.x >> 2;   // 0..63
    int q  = threadIdx.x & 3;    // col quarter
    int r0 = blockIdx.x * 128 + tg * 2;
    if (r0 >= M) return;
    int r1 = r0 + 1;

    float acc0[32], acc1[32];
#pragma unroll
    for (int j = 0; j < 32; j++) { acc0[j] = 0.f; acc1[j] = 0.f; }

    const float4* x0 = (const float4*)(X + (size_t)r0 * 128);
    const float4* x1 = (const float4*)(X + (size_t)r1 * 128);

    for (int k4 = 0; k4 < 32; k4++) {
        float a0[4], a1[4];
        *(float4*)a0 = x0[k4];
        *(float4*)a1 = x1[k4];
#pragma unroll
        for (int kk = 0; kk < 4; kk++) {
            const float4* wr = (const float4*)(&Wl[(k4 * 4 + kk) * 128 + q * 32]);
#pragma unroll
            for (int j4 = 0; j4 < 8; j4++) {
                float4 w = wr[j4];
                acc0[j4 * 4 + 0] += a0[kk] * w.x;
                acc0[j4 * 4 + 1] += a0[kk] * w.y;
                acc0[j4 * 4 + 2] += a0[kk] * w.z;
                acc0[j4 * 4 + 3] += a0[kk] * w.w;
                acc1[j4 * 4 + 0] += a1[kk] * w.x;
                acc1[j4 * 4 + 1] += a1[kk] * w.y;
                acc1[j4 * 4 + 2] += a1[kk] * w.z;
                acc1[j4 * 4 + 3] += a1[kk] * w.w;
            }
        }
    }

    uint4* Y4 = (uint4*)Y;  // 16B = 8 bf16 per uint4; row stride 16
#pragma unroll
    for (int g = 0; g < 4; g++) {
        Y4[(size_t)r0 * 16 + q * 4 + g] = pack8(&acc0[g * 8]);
        Y4[(size_t)r1 * 16 + q * 4 + g] = pack8(&acc1[g * 8]);
    }
}

// ---------------- GEMM (bf16 input): Y_bf16[M,128] = X_bf16[M,128] @ W[128,128] ----------------
__global__ __launch_bounds__(256) void gemm_bf16in_kernel(const ushort* __restrict__ X,
                                                          const float* __restrict__ W,
                                                          ushort* __restrict__ Y, int M) {
    __shared__ float Wl[128 * 128];
    {
        const float4* W4 = (const float4*)W;
        float4* Wl4 = (float4*)Wl;
        for (int t = threadIdx.x; t < 128 * 128 / 4; t += 256) Wl4[t] = W4[t];
    }
    __syncthreads();

    int tg = threadIdx.x >> 2;
    int q  = threadIdx.x & 3;
    int r0 = blockIdx.x * 128 + tg * 2;
    if (r0 >= M) return;
    int r1 = r0 + 1;

    float acc0[32], acc1[32];
#pragma unroll
    for (int j = 0; j < 32; j++) { acc0[j] = 0.f; acc1[j] = 0.f; }

    const uint4* x0 = (const uint4*)(X + (size_t)r0 * 128);  // 16 chunks of 8 bf16
    const uint4* x1 = (const uint4*)(X + (size_t)r1 * 128);

    for (int k8 = 0; k8 < 16; k8++) {
        float a0[8], a1[8];
        unpack8(x0[k8], a0);
        unpack8(x1[k8], a1);
#pragma unroll
        for (int kk = 0; kk < 8; kk++) {
            const float4* wr = (const float4*)(&Wl[(k8 * 8 + kk) * 128 + q * 32]);
#pragma unroll
            for (int j4 = 0; j4 < 8; j4++) {
                float4 w = wr[j4];
                acc0[j4 * 4 + 0] += a0[kk] * w.x;
                acc0[j4 * 4 + 1] += a0[kk] * w.y;
                acc0[j4 * 4 + 2] += a0[kk] * w.z;
                acc0[j4 * 4 + 3] += a0[kk] * w.w;
                acc1[j4 * 4 + 0] += a1[kk] * w.x;
                acc1[j4 * 4 + 1] += a1[kk] * w.y;
                acc1[j4 * 4 + 2] += a1[kk] * w.z;
                acc1[j4 * 4 + 3] += a1[kk] * w.w;
            }
        }
    }

    uint4* Y4 = (uint4*)Y;
#pragma unroll
    for (int g = 0; g < 4; g++) {
        Y4[(size_t)r0 * 16 + q * 4 + g] = pack8(&acc0[g * 8]);
        Y4[(size_t)r1 * 16 + q * 4 + g] = pack8(&acc1[g * 8]);
    }
}

// ---------------- aggregation: one wave per node, quarter-wave per neighbor row ----------------
// bf16 rows (256B); 16 lanes x uint4 = one row. 4 rows/iter, unrolled x2 -> 8 in flight.
__global__ __launch_bounds__(256) void aggregate_kernel(
    const ushort* __restrict__ T, const int* __restrict__ csr,
    const int* __restrict__ rowptr, const int* __restrict__ degi,
    const float* __restrict__ dis, const float* __restrict__ bias,
    ushort* __restrict__ H) {
    int node = blockIdx.x * 4 + (threadIdx.x >> 6);
    int lane = threadIdx.x & 63;
    if (node >= N_NODES) return;
    int group = lane >> 4;   // 0..3: which neighbor in the 4-batch
    int sub   = lane & 15;   // which 8-col chunk of the row

    float di = dis[node];
    int start = rowptr[node];
    int cnt = degi[node];
    const uint4* T4 = (const uint4*)T;  // row stride = 16 uint4

    float acc[8];
#pragma unroll
    for (int i = 0; i < 8; i++) acc[i] = 0.f;

    int j = group;
    for (; j + 4 < cnt; j += 8) {
        int s0 = csr[start + j];
        int s1 = csr[start + j + 4];
        float c0 = di * dis[s0];
        float c1 = di * dis[s1];
        uint4 v0 = T4[(size_t)s0 * 16 + sub];
        uint4 v1 = T4[(size_t)s1 * 16 + sub];
        float f0[8], f1[8];
        unpack8(v0, f0);
        unpack8(v1, f1);
#pragma unroll
        for (int i = 0; i < 8; i++) acc[i] += c0 * f0[i] + c1 * f1[i];
    }
    if (j < cnt) {
        int s0 = csr[start + j];
        float c0 = di * dis[s0];
        uint4 v0 = T4[(size_t)s0 * 16 + sub];
        float f0[8];
        unpack8(v0, f0);
#pragma unroll
        for (int i = 0; i < 8; i++) acc[i] += c0 * f0[i];
    }

    // reduce the 4 neighbor-groups
#pragma unroll
    for (int i = 0; i < 8; i++) {
        acc[i] += __shfl_xor(acc[i], 16);
        acc[i] += __shfl_xor(acc[i], 32);
    }

    if (group == 0) {
        // self-loop + bias + relu, write row
        uint4 sv = T4[(size_t)node * 16 + sub];
        float sf[8];
        unpack8(sv, sf);
        float invdeg = di * di;
        float4 blo = ((const float4*)bias)[sub * 2];
        float4 bhi = ((const float4*)bias)[sub * 2 + 1];
        float bb[8] = {blo.x, blo.y, blo.z, blo.w, bhi.x, bhi.y, bhi.z, bhi.w};
        float r[8];
#pragma unroll
        for (int i = 0; i < 8; i++) r[i] = fmaxf(acc[i] + invdeg * sf[i] + bb[i], 0.f);
        ((uint4*)H)[(size_t)node * 16 + sub] = pack8(r);
    }
}

// ---------------- pool: chunked per-wave run-accumulation over sorted batch ----------------
__global__ __launch_bounds__(256) void pool_kernel(const ushort* __restrict__ H,
                                                   const int* __restrict__ batch,
                                                   const float* __restrict__ Wfc,
                                                   float* __restrict__ gsum) {
    int wave = threadIdx.x >> 6;
    int lane = threadIdx.x & 63;
    int wid = blockIdx.x * 4 + wave;
    const int nwaves = POOL_BLOCKS * 4;
    const int per = (N_NODES + nwaves - 1) / nwaves;
    int start = wid * per;
    int end = min(start + per, N_NODES);
    if (start >= end) return;

    const uint* H1 = (const uint*)H;  // 2 bf16 per uint; row stride 64
    float2 w = ((const float2*)Wfc)[lane];
    float2 acc = make_float2(0.f, 0.f);
    int gcur = batch[start];

    for (int node = start; node < end; ++node) {
        int g = batch[node];
        if (g != gcur) {
            float d = acc.x * w.x + acc.y * w.y;
#pragma unroll
            for (int off = 32; off > 0; off >>= 1) d += __shfl_down(d, off);
            if (lane == 0) atomicAdd(&gsum[gcur], d);
            acc = make_float2(0.f, 0.f);
            gcur = g;
        }
        uint v = H1[(size_t)node * 64 + lane];
        acc.x += bf2f((ushort)(v & 0xFFFF));
        acc.y += bf2f((ushort)(v >> 16));
    }
    float d = acc.x * w.x + acc.y * w.y;
#pragma unroll
    for (int off = 32; off > 0; off >>= 1) d += __shfl_down(d, off);
    if (lane == 0) atomicAdd(&gsum[gcur], d);
}

// ---------------- finalize: counts via binary search on sorted batch ----------------
__global__ void finalize_kernel(const float* __restrict__ gsum, const int* __restrict__ batch,
                                const float* __restrict__ bfc, float* __restrict__ out) {
    int g = threadIdx.x;
    if (g >= N_GRAPHS) return;
    auto lb = [&](int key) {
        int lo = 0, hi = N_NODES;
        while (lo < hi) {
            int mid = (lo + hi) >> 1;
            if (batch[mid] < key) lo = mid + 1; else hi = mid;
        }
        return lo;
    };
    int a = lb(g), b = lb(g + 1);
    float cnt = (float)(b - a);
    out[g] = gsum[g] / fmaxf(cnt, 1.0f) + bfc[0];
}

// ---------------- launcher ----------------
extern "C" void kernel_launch(void* const* d_in, const int* in_sizes, int n_in,
                              void* d_out, int out_size, void* d_ws, size_t ws_size,
                              hipStream_t stream) {
    const float* x    = (const float*)d_in[0];
    const int*   eidx = (const int*)d_in[1];
    const int*   batch= (const int*)d_in[2];
    const float* W1   = (const float*)d_in[3];
    const float* b1   = (const float*)d_in[4];
    const float* W2   = (const float*)d_in[5];
    const float* b2   = (const float*)d_in[6];
    const float* Wfc  = (const float*)d_in[7];
    const float* bfc  = (const float*)d_in[8];
    float* out = (float*)d_out;

    const int* src = eidx;
    const int* dst = eidx + N_EDGES;

    size_t off = 0;
    char* base = (char*)d_ws;
    auto alloc = [&](size_t bytes) -> void* {
        void* p = base + off;
        off += (bytes + 255) & ~(size_t)255;
        return p;
    };
    // zeroed region first: degi, fill, gsum
    int*    degi   = (int*)alloc(N_NODES * 4);
    int*    fill   = (int*)alloc(N_NODES * 4);
    float*  gsum   = (float*)alloc(N_GRAPHS * 4);
    size_t zero_bytes = off;
    ushort* A      = (ushort*)alloc((size_t)N_NODES * HID * 2);
    ushort* B      = (ushort*)alloc((size_t)N_NODES * HID * 2);
    int*    incl   = (int*)alloc(N_NODES * 4);
    int*    rowptr = (int*)alloc(N_NODES * 4);
    float*  dis    = (float*)alloc(N_NODES * 4);
    int*    csr    = (int*)alloc(N_EDGES * 4);
    int*    bsum   = (int*)alloc(1024);

    int zn = (int)(zero_bytes / 4);
    zero_kernel<<<(zn + 255) / 256, 256, 0, stream>>>((int*)base, zn);

    deg_kernel<<<(N_EDGES + 255) / 256, 256, 0, stream>>>(dst, degi);
    dis_kernel<<<(N_NODES + 255) / 256, 256, 0, stream>>>(degi, dis);

    int nb = (N_NODES + 1023) / 1024;  // 98
    scan1<<<nb, 1024, 0, stream>>>(degi, incl, bsum);
    scan2<<<1, 128, 0, stream>>>(bsum, nb);
    rowptr_kernel<<<(N_NODES + 255) / 256, 256, 0, stream>>>(incl, degi, bsum, rowptr);
    scatter_kernel<<<(N_EDGES + 255) / 256, 256, 0, stream>>>(src, dst, rowptr, fill, csr);

    int gemm_grid = (N_NODES + 127) / 128;
    int agg_grid  = (N_NODES + 3) / 4;

    // layer 1
    gemm_f32in_kernel<<<gemm_grid, 256, 0, stream>>>(x, W1, A, N_NODES);
    aggregate_kernel<<<agg_grid, 256, 0, stream>>>(A, csr, rowptr, degi, dis, b1, B);
    // layer 2
    gemm_bf16in_kernel<<<gemm_grid, 256, 0, stream>>>(B, W2, A, N_NODES);
    aggregate_kernel<<<agg_grid, 256, 0, stream>>>(A, csr, rowptr, degi, dis, b2, B);

    // pool + fc
    pool_kernel<<<POOL_BLOCKS, 256, 0, stream>>>(B, batch, Wfc, gsum);
    finalize_kernel<<<1, 256, 0, stream>>>(gsum, batch, bfc, out);
}

// Round 4
// 393.370 us; speedup vs baseline: 2.5354x; 1.2848x over previous
//
#include <hip/hip_runtime.h>

#define N_NODES 100000
#define N_EDGES 1600000
#define HID 128
#define N_GRAPHS 256
#define POOL_BLOCKS 512

typedef unsigned int uint;
typedef unsigned short ushort;
typedef short short8 __attribute__((ext_vector_type(8)));
typedef float f32x4 __attribute__((ext_vector_type(4)));

__device__ __forceinline__ float bf2f(ushort u) {
    return __uint_as_float(((uint)u) << 16);
}
__device__ __forceinline__ ushort f2bf(float f) {
    uint u = __float_as_uint(f);
    u += 0x7FFFu + ((u >> 16) & 1u);   // round-to-nearest-even
    return (ushort)(u >> 16);
}
__device__ __forceinline__ void unpack8(uint4 v, float* o) {
    o[0] = bf2f((ushort)(v.x & 0xFFFF)); o[1] = bf2f((ushort)(v.x >> 16));
    o[2] = bf2f((ushort)(v.y & 0xFFFF)); o[3] = bf2f((ushort)(v.y >> 16));
    o[4] = bf2f((ushort)(v.z & 0xFFFF)); o[5] = bf2f((ushort)(v.z >> 16));
    o[6] = bf2f((ushort)(v.w & 0xFFFF)); o[7] = bf2f((ushort)(v.w >> 16));
}
__device__ __forceinline__ uint4 pack8(const float* r) {
    uint4 o;
    o.x = (uint)f2bf(r[0]) | ((uint)f2bf(r[1]) << 16);
    o.y = (uint)f2bf(r[2]) | ((uint)f2bf(r[3]) << 16);
    o.z = (uint)f2bf(r[4]) | ((uint)f2bf(r[5]) << 16);
    o.w = (uint)f2bf(r[6]) | ((uint)f2bf(r[7]) << 16);
    return o;
}

union Frag16 {
    uint4 u;
    short8 s;
    ushort h[8];
};

// ---------------- zero ----------------
__global__ void zero_kernel(int* __restrict__ p, int n) {
    int i = blockIdx.x * blockDim.x + threadIdx.x;
    if (i < n) p[i] = 0;
}

// ---------------- degree ----------------
__global__ void deg_kernel(const int* __restrict__ dst, int* __restrict__ degi) {
    int e = blockIdx.x * blockDim.x + threadIdx.x;
    if (e < N_EDGES) atomicAdd(&degi[dst[e]], 1);
}

__global__ void dis_kernel(const int* __restrict__ degi, float* __restrict__ dis) {
    int i = blockIdx.x * blockDim.x + threadIdx.x;
    if (i < N_NODES) dis[i] = rsqrtf(1.0f + (float)degi[i]);
}

// ---------------- scan (CSR rowptr) ----------------
__global__ __launch_bounds__(1024) void scan1(const int* __restrict__ degi,
                                              int* __restrict__ incl,
                                              int* __restrict__ bsum) {
    __shared__ int s[1024];
    int i = blockIdx.x * 1024 + threadIdx.x;
    int v = (i < N_NODES) ? degi[i] : 0;
    s[threadIdx.x] = v;
    __syncthreads();
    for (int off = 1; off < 1024; off <<= 1) {
        int t = (threadIdx.x >= off) ? s[threadIdx.x - off] : 0;
        __syncthreads();
        s[threadIdx.x] += t;
        __syncthreads();
    }
    if (i < N_NODES) incl[i] = s[threadIdx.x];
    if (threadIdx.x == 1023) bsum[blockIdx.x] = s[1023];
}

__global__ void scan2(int* __restrict__ bsum, int nb) {
    __shared__ int s[128];
    int t = threadIdx.x;
    int v = (t < nb) ? bsum[t] : 0;
    s[t] = v;
    __syncthreads();
    for (int off = 1; off < 128; off <<= 1) {
        int a = (t >= off) ? s[t - off] : 0;
        __syncthreads();
        s[t] += a;
        __syncthreads();
    }
    if (t < nb) bsum[t] = s[t] - v;  // exclusive base per block
}

__global__ void rowptr_kernel(const int* __restrict__ incl, const int* __restrict__ degi,
                              const int* __restrict__ bsum, int* __restrict__ rowptr) {
    int i = blockIdx.x * blockDim.x + threadIdx.x;
    if (i < N_NODES) rowptr[i] = incl[i] - degi[i] + bsum[i >> 10];
}

__global__ void scatter_kernel(const int* __restrict__ src, const int* __restrict__ dst,
                               const int* __restrict__ rowptr, int* __restrict__ fill,
                               int* __restrict__ csr) {
    int e = blockIdx.x * blockDim.x + threadIdx.x;
    if (e < N_EDGES) {
        int d = dst[e];
        int pos = rowptr[d] + atomicAdd(&fill[d], 1);
        csr[pos] = src[e];
    }
}

// ---------------- W -> B-fragment pre-pack ----------------
// WB[(kt*8+nt)*64 + lane] holds 8 bf16: W[kt*32+(lane>>4)*8+j][nt*16+(lane&15)], j=0..7
__global__ void prep_wfrag(const float* __restrict__ W, uint4* __restrict__ WB) {
    int t = blockIdx.x * 256 + threadIdx.x;
    if (t >= 2048) return;
    int lane = t & 63;
    int nt = (t >> 6) & 7;
    int kt = t >> 9;
    int kbase = kt * 32 + (lane >> 4) * 8;
    int col = nt * 16 + (lane & 15);
    float r[8];
#pragma unroll
    for (int j = 0; j < 8; j++) r[j] = W[(size_t)(kbase + j) * 128 + col];
    WB[t] = pack8(r);
}

// ---------------- MFMA GEMM: Y_bf16[M,128] = X[M,128] @ W  (W pre-packed frags) ----------------
// Block: 256 thr (4 waves), 128 rows. Wave: 32 rows (2 x 16-row tiles), 64 MFMAs.
template <bool F32IN>
__global__ __launch_bounds__(256) void mgemm_kernel(const void* __restrict__ Xv,
                                                    const uint4* __restrict__ WB,
                                                    ushort* __restrict__ Y, int M) {
    __shared__ uint4 WBs[2048];
#pragma unroll
    for (int i = 0; i < 8; i++) WBs[i * 256 + threadIdx.x] = WB[i * 256 + threadIdx.x];
    __syncthreads();

    int wave = threadIdx.x >> 6;
    int lane = threadIdx.x & 63;
    int r0 = blockIdx.x * 128 + wave * 32;
    if (r0 >= M) return;  // whole-wave guard (M % 32 == 0)

    int rowA = lane & 15;
    int ksub = (lane >> 4) * 8;  // 0,8,16,24

    Frag16 a[2][4];
#pragma unroll
    for (int rt = 0; rt < 2; ++rt) {
        int row = r0 + rt * 16 + rowA;
        if (F32IN) {
            const float* xr = (const float*)Xv + (size_t)row * 128;
#pragma unroll
            for (int kt = 0; kt < 4; ++kt) {
                float4 lo = *(const float4*)(xr + kt * 32 + ksub);
                float4 hi = *(const float4*)(xr + kt * 32 + ksub + 4);
                float r[8] = {lo.x, lo.y, lo.z, lo.w, hi.x, hi.y, hi.z, hi.w};
                a[rt][kt].u = pack8(r);
            }
        } else {
            const uint4* xr = (const uint4*)Xv + (size_t)row * 16;
#pragma unroll
            for (int kt = 0; kt < 4; ++kt) a[rt][kt].u = xr[kt * 4 + (lane >> 4)];
        }
    }

    f32x4 acc[2][8];
#pragma unroll
    for (int rt = 0; rt < 2; ++rt)
#pragma unroll
        for (int nt = 0; nt < 8; ++nt) acc[rt][nt] = (f32x4){0.f, 0.f, 0.f, 0.f};

#pragma unroll
    for (int kt = 0; kt < 4; ++kt) {
#pragma unroll
        for (int nt = 0; nt < 8; ++nt) {
            Frag16 b;
            b.u = WBs[(kt * 8 + nt) * 64 + lane];
            acc[0][nt] = __builtin_amdgcn_mfma_f32_16x16x32_bf16(a[0][kt].s, b.s, acc[0][nt], 0, 0, 0);
            acc[1][nt] = __builtin_amdgcn_mfma_f32_16x16x32_bf16(a[1][kt].s, b.s, acc[1][nt], 0, 0, 0);
        }
    }

    // C/D layout: col = lane&15, row = (lane>>4)*4 + reg
    int cbase = lane & 15;
#pragma unroll
    for (int rt = 0; rt < 2; ++rt) {
        int rbase = r0 + rt * 16 + (lane >> 4) * 4;
#pragma unroll
        for (int nt = 0; nt < 8; ++nt) {
#pragma unroll
            for (int j = 0; j < 4; ++j) {
                Y[(size_t)(rbase + j) * 128 + nt * 16 + cbase] = f2bf(acc[rt][nt][j]);
            }
        }
    }
}

// ---------------- aggregation: one wave per node, quarter-wave per neighbor row ----------------
__global__ __launch_bounds__(256) void aggregate_kernel(
    const ushort* __restrict__ T, const int* __restrict__ csr,
    const int* __restrict__ rowptr, const int* __restrict__ degi,
    const float* __restrict__ dis, const float* __restrict__ bias,
    ushort* __restrict__ H) {
    int node = blockIdx.x * 4 + (threadIdx.x >> 6);
    int lane = threadIdx.x & 63;
    if (node >= N_NODES) return;
    int group = lane >> 4;
    int sub   = lane & 15;

    float di = dis[node];
    int start = rowptr[node];
    int cnt = degi[node];
    const uint4* T4 = (const uint4*)T;

    float acc[8];
#pragma unroll
    for (int i = 0; i < 8; i++) acc[i] = 0.f;

    int j = group;
    for (; j + 4 < cnt; j += 8) {
        int s0 = csr[start + j];
        int s1 = csr[start + j + 4];
        float c0 = di * dis[s0];
        float c1 = di * dis[s1];
        uint4 v0 = T4[(size_t)s0 * 16 + sub];
        uint4 v1 = T4[(size_t)s1 * 16 + sub];
        float f0[8], f1[8];
        unpack8(v0, f0);
        unpack8(v1, f1);
#pragma unroll
        for (int i = 0; i < 8; i++) acc[i] += c0 * f0[i] + c1 * f1[i];
    }
    if (j < cnt) {
        int s0 = csr[start + j];
        float c0 = di * dis[s0];
        uint4 v0 = T4[(size_t)s0 * 16 + sub];
        float f0[8];
        unpack8(v0, f0);
#pragma unroll
        for (int i = 0; i < 8; i++) acc[i] += c0 * f0[i];
    }

#pragma unroll
    for (int i = 0; i < 8; i++) {
        acc[i] += __shfl_xor(acc[i], 16);
        acc[i] += __shfl_xor(acc[i], 32);
    }

    if (group == 0) {
        uint4 sv = T4[(size_t)node * 16 + sub];
        float sf[8];
        unpack8(sv, sf);
        float invdeg = di * di;
        float4 blo = ((const float4*)bias)[sub * 2];
        float4 bhi = ((const float4*)bias)[sub * 2 + 1];
        float bb[8] = {blo.x, blo.y, blo.z, blo.w, bhi.x, bhi.y, bhi.z, bhi.w};
        float r[8];
#pragma unroll
        for (int i = 0; i < 8; i++) r[i] = fmaxf(acc[i] + invdeg * sf[i] + bb[i], 0.f);
        ((uint4*)H)[(size_t)node * 16 + sub] = pack8(r);
    }
}

// ---------------- pool: chunked per-wave run-accumulation over sorted batch ----------------
__global__ __launch_bounds__(256) void pool_kernel(const ushort* __restrict__ H,
                                                   const int* __restrict__ batch,
                                                   const float* __restrict__ Wfc,
                                                   float* __restrict__ gsum) {
    int wave = threadIdx.x >> 6;
    int lane = threadIdx.x & 63;
    int wid = blockIdx.x * 4 + wave;
    const int nwaves = POOL_BLOCKS * 4;
    const int per = (N_NODES + nwaves - 1) / nwaves;
    int start = wid * per;
    int end = min(start + per, N_NODES);
    if (start >= end) return;

    const uint* H1 = (const uint*)H;
    float2 w = ((const float2*)Wfc)[lane];
    float2 acc = make_float2(0.f, 0.f);
    int gcur = batch[start];

    for (int node = start; node < end; ++node) {
        int g = batch[node];
        if (g != gcur) {
            float d = acc.x * w.x + acc.y * w.y;
#pragma unroll
            for (int off = 32; off > 0; off >>= 1) d += __shfl_down(d, off);
            if (lane == 0) atomicAdd(&gsum[gcur], d);
            acc = make_float2(0.f, 0.f);
            gcur = g;
        }
        uint v = H1[(size_t)node * 64 + lane];
        acc.x += bf2f((ushort)(v & 0xFFFF));
        acc.y += bf2f((ushort)(v >> 16));
    }
    float d = acc.x * w.x + acc.y * w.y;
#pragma unroll
    for (int off = 32; off > 0; off >>= 1) d += __shfl_down(d, off);
    if (lane == 0) atomicAdd(&gsum[gcur], d);
}

// ---------------- finalize ----------------
__global__ void finalize_kernel(const float* __restrict__ gsum, const int* __restrict__ batch,
                                const float* __restrict__ bfc, float* __restrict__ out) {
    int g = threadIdx.x;
    if (g >= N_GRAPHS) return;
    auto lb = [&](int key) {
        int lo = 0, hi = N_NODES;
        while (lo < hi) {
            int mid = (lo + hi) >> 1;
            if (batch[mid] < key) lo = mid + 1; else hi = mid;
        }
        return lo;
    };
    int a = lb(g), b = lb(g + 1);
    float cnt = (float)(b - a);
    out[g] = gsum[g] / fmaxf(cnt, 1.0f) + bfc[0];
}

// ---------------- launcher ----------------
extern "C" void kernel_launch(void* const* d_in, const int* in_sizes, int n_in,
                              void* d_out, int out_size, void* d_ws, size_t ws_size,
                              hipStream_t stream) {
    const float* x    = (const float*)d_in[0];
    const int*   eidx = (const int*)d_in[1];
    const int*   batch= (const int*)d_in[2];
    const float* W1   = (const float*)d_in[3];
    const float* b1   = (const float*)d_in[4];
    const float* W2   = (const float*)d_in[5];
    const float* b2   = (const float*)d_in[6];
    const float* Wfc  = (const float*)d_in[7];
    const float* bfc  = (const float*)d_in[8];
    float* out = (float*)d_out;

    const int* src = eidx;
    const int* dst = eidx + N_EDGES;

    size_t off = 0;
    char* base = (char*)d_ws;
    auto alloc = [&](size_t bytes) -> void* {
        void* p = base + off;
        off += (bytes + 255) & ~(size_t)255;
        return p;
    };
    // zeroed region first: degi, fill, gsum
    int*    degi   = (int*)alloc(N_NODES * 4);
    int*    fill   = (int*)alloc(N_NODES * 4);
    float*  gsum   = (float*)alloc(N_GRAPHS * 4);
    size_t zero_bytes = off;
    ushort* A      = (ushort*)alloc((size_t)N_NODES * HID * 2);
    ushort* B      = (ushort*)alloc((size_t)N_NODES * HID * 2);
    int*    incl   = (int*)alloc(N_NODES * 4);
    int*    rowptr = (int*)alloc(N_NODES * 4);
    float*  dis    = (float*)alloc(N_NODES * 4);
    int*    csr    = (int*)alloc(N_EDGES * 4);
    int*    bsum   = (int*)alloc(1024);
    uint4*  WB1    = (uint4*)alloc(2048 * 16);
    uint4*  WB2    = (uint4*)alloc(2048 * 16);

    int zn = (int)(zero_bytes / 4);
    zero_kernel<<<(zn + 255) / 256, 256, 0, stream>>>((int*)base, zn);

    deg_kernel<<<(N_EDGES + 255) / 256, 256, 0, stream>>>(dst, degi);
    dis_kernel<<<(N_NODES + 255) / 256, 256, 0, stream>>>(degi, dis);

    int nb = (N_NODES + 1023) / 1024;  // 98
    scan1<<<nb, 1024, 0, stream>>>(degi, incl, bsum);
    scan2<<<1, 128, 0, stream>>>(bsum, nb);
    rowptr_kernel<<<(N_NODES + 255) / 256, 256, 0, stream>>>(incl, degi, bsum, rowptr);
    scatter_kernel<<<(N_EDGES + 255) / 256, 256, 0, stream>>>(src, dst, rowptr, fill, csr);

    // W fragment pre-pack
    prep_wfrag<<<8, 256, 0, stream>>>(W1, WB1);
    prep_wfrag<<<8, 256, 0, stream>>>(W2, WB2);

    int gemm_grid = (N_NODES + 127) / 128;
    int agg_grid  = (N_NODES + 3) / 4;

    // layer 1
    mgemm_kernel<true><<<gemm_grid, 256, 0, stream>>>(x, WB1, A, N_NODES);
    aggregate_kernel<<<agg_grid, 256, 0, stream>>>(A, csr, rowptr, degi, dis, b1, B);
    // layer 2
    mgemm_kernel<false><<<gemm_grid, 256, 0, stream>>>(B, WB2, A, N_NODES);
    aggregate_kernel<<<agg_grid, 256, 0, stream>>>(A, csr, rowptr, degi, dis, b2, B);

    // pool + fc
    pool_kernel<<<POOL_BLOCKS, 256, 0, stream>>>(B, batch, Wfc, gsum);
    finalize_kernel<<<1, 256, 0, stream>>>(gsum, batch, bfc, out);
}

// Round 5
// 271.359 us; speedup vs baseline: 3.6754x; 1.4496x over previous
//
#include <hip/hip_runtime.h>

#define N_NODES 100000
#define N_EDGES 1600000
#define HID 128
#define N_GRAPHS 256
#define POOL_BLOCKS 512

#define BSHIFT 9
#define BSIZE 512
#define NBUCK ((N_NODES + BSIZE - 1) / BSIZE)   // 196
#define EPB 8192
#define NBLK_A ((N_EDGES + EPB - 1) / EPB)      // 196

typedef unsigned int uint;
typedef unsigned short ushort;
typedef short short8 __attribute__((ext_vector_type(8)));
typedef float f32x4 __attribute__((ext_vector_type(4)));

__device__ __forceinline__ float bf2f(ushort u) {
    return __uint_as_float(((uint)u) << 16);
}
__device__ __forceinline__ ushort f2bf(float f) {
    uint u = __float_as_uint(f);
    u += 0x7FFFu + ((u >> 16) & 1u);   // round-to-nearest-even
    return (ushort)(u >> 16);
}
__device__ __forceinline__ void unpack8(uint4 v, float* o) {
    o[0] = bf2f((ushort)(v.x & 0xFFFF)); o[1] = bf2f((ushort)(v.x >> 16));
    o[2] = bf2f((ushort)(v.y & 0xFFFF)); o[3] = bf2f((ushort)(v.y >> 16));
    o[4] = bf2f((ushort)(v.z & 0xFFFF)); o[5] = bf2f((ushort)(v.z >> 16));
    o[6] = bf2f((ushort)(v.w & 0xFFFF)); o[7] = bf2f((ushort)(v.w >> 16));
}
__device__ __forceinline__ uint4 pack8(const float* r) {
    uint4 o;
    o.x = (uint)f2bf(r[0]) | ((uint)f2bf(r[1]) << 16);
    o.y = (uint)f2bf(r[2]) | ((uint)f2bf(r[3]) << 16);
    o.z = (uint)f2bf(r[4]) | ((uint)f2bf(r[5]) << 16);
    o.w = (uint)f2bf(r[6]) | ((uint)f2bf(r[7]) << 16);
    return o;
}

union Frag16 {
    uint4 u;
    short8 s;
    ushort h[8];
};

// ---------------- zero ----------------
__global__ void zero_kernel(int* __restrict__ p, int n) {
    int i = blockIdx.x * blockDim.x + threadIdx.x;
    if (i < n) p[i] = 0;
}

// ---------------- bucketed CSR build ----------------
// Pass 1: per-block LDS histogram over 196 buckets of 512 nodes
__global__ __launch_bounds__(256) void hist_kernel(const int* __restrict__ dst,
                                                   int* __restrict__ bcnt) {
    __shared__ int h[NBUCK];
    for (int t = threadIdx.x; t < NBUCK; t += 256) h[t] = 0;
    __syncthreads();
    int base = blockIdx.x * EPB;
#pragma unroll 4
    for (int it = 0; it < EPB / 256; ++it) {
        int e = base + it * 256 + threadIdx.x;
        if (e < N_EDGES) atomicAdd(&h[dst[e] >> BSHIFT], 1);
    }
    __syncthreads();
    for (int t = threadIdx.x; t < NBUCK; t += 256)
        if (h[t]) atomicAdd(&bcnt[t], h[t]);
}

// Pass 2: exclusive scan of bucket counts (1 block)
__global__ __launch_bounds__(256) void bscan_kernel(const int* __restrict__ bcnt,
                                                    int* __restrict__ bbase) {
    __shared__ int s[256];
    int t = threadIdx.x;
    int v = (t < NBUCK) ? bcnt[t] : 0;
    s[t] = v;
    __syncthreads();
    for (int off = 1; off < 256; off <<= 1) {
        int a = (t >= off) ? s[t - off] : 0;
        __syncthreads();
        s[t] += a;
        __syncthreads();
    }
    if (t < NBUCK) bbase[t] = s[t] - v;
    if (t == NBUCK - 1) bbase[NBUCK] = s[t];
}

// Pass 3: scatter packed edges into bucket regions (per-block reserved runs)
__global__ __launch_bounds__(256) void bucket_scatter_kernel(const int* __restrict__ src,
                                                             const int* __restrict__ dst,
                                                             const int* __restrict__ bbase,
                                                             int* __restrict__ bfill,
                                                             uint* __restrict__ bucketed) {
    __shared__ int h[NBUCK];
    __shared__ int rb[NBUCK];
    for (int t = threadIdx.x; t < NBUCK; t += 256) h[t] = 0;
    __syncthreads();
    int base = blockIdx.x * EPB;
#pragma unroll 4
    for (int it = 0; it < EPB / 256; ++it) {
        int e = base + it * 256 + threadIdx.x;
        if (e < N_EDGES) atomicAdd(&h[dst[e] >> BSHIFT], 1);
    }
    __syncthreads();
    for (int t = threadIdx.x; t < NBUCK; t += 256) {
        rb[t] = h[t] ? atomicAdd(&bfill[t], h[t]) : 0;
        h[t] = 0;
    }
    __syncthreads();
#pragma unroll 4
    for (int it = 0; it < EPB / 256; ++it) {
        int e = base + it * 256 + threadIdx.x;
        if (e < N_EDGES) {
            int d = dst[e];
            int b = d >> BSHIFT;
            int pos = bbase[b] + rb[b] + atomicAdd(&h[b], 1);
            bucketed[pos] = (uint)src[e] | ((uint)(d & (BSIZE - 1)) << 17);
        }
    }
}

// Pass 4: one block per bucket -> local count/scan/scatter; contiguous global writes
__global__ __launch_bounds__(256) void bucket_csr_kernel(const uint* __restrict__ bucketed,
                                                         const int* __restrict__ bbase,
                                                         int* __restrict__ degi,
                                                         int* __restrict__ rowptr,
                                                         int* __restrict__ csr) {
    int b = blockIdx.x;
    int beg = bbase[b], end = bbase[b + 1];
    int ne = end - beg;
    __shared__ int cnt[BSIZE];
    __shared__ int fl[BSIZE];
    __shared__ int ex[BSIZE];
    __shared__ int ps[256];
    int t = threadIdx.x;
    cnt[t] = 0; cnt[t + 256] = 0;
    fl[t] = 0;  fl[t + 256] = 0;
    __syncthreads();
    for (int i = t; i < ne; i += 256) atomicAdd(&cnt[bucketed[beg + i] >> 17], 1);
    __syncthreads();
    int v0 = cnt[2 * t], v1 = cnt[2 * t + 1];
    int s = v0 + v1;
    ps[t] = s;
    __syncthreads();
    for (int off = 1; off < 256; off <<= 1) {
        int a = (t >= off) ? ps[t - off] : 0;
        __syncthreads();
        ps[t] += a;
        __syncthreads();
    }
    int e0 = ps[t] - s;
    ex[2 * t] = e0;
    ex[2 * t + 1] = e0 + v0;
    int g = b * BSIZE + 2 * t;
    if (g < N_NODES) { degi[g] = v0; rowptr[g] = beg + e0; }
    if (g + 1 < N_NODES) { degi[g + 1] = v1; rowptr[g + 1] = beg + e0 + v0; }
    __syncthreads();
    for (int i = t; i < ne; i += 256) {
        uint u = bucketed[beg + i];
        int dl = u >> 17;
        int p = ex[dl] + atomicAdd(&fl[dl], 1);
        csr[beg + p] = (int)(u & 0x1FFFF);
    }
}

__global__ void dis_kernel(const int* __restrict__ degi, float* __restrict__ dis) {
    int i = blockIdx.x * blockDim.x + threadIdx.x;
    if (i < N_NODES) dis[i] = rsqrtf(1.0f + (float)degi[i]);
}

// ---------------- W -> B-fragment pre-pack ----------------
__global__ void prep_wfrag(const float* __restrict__ W, uint4* __restrict__ WB) {
    int t = blockIdx.x * 256 + threadIdx.x;
    if (t >= 2048) return;
    int lane = t & 63;
    int nt = (t >> 6) & 7;
    int kt = t >> 9;
    int kbase = kt * 32 + (lane >> 4) * 8;
    int col = nt * 16 + (lane & 15);
    float r[8];
#pragma unroll
    for (int j = 0; j < 8; j++) r[j] = W[(size_t)(kbase + j) * 128 + col];
    WB[t] = pack8(r);
}

// ---------------- MFMA GEMM ----------------
template <bool F32IN>
__global__ __launch_bounds__(256) void mgemm_kernel(const void* __restrict__ Xv,
                                                    const uint4* __restrict__ WB,
                                                    ushort* __restrict__ Y, int M) {
    __shared__ uint4 WBs[2048];
#pragma unroll
    for (int i = 0; i < 8; i++) WBs[i * 256 + threadIdx.x] = WB[i * 256 + threadIdx.x];
    __syncthreads();

    int wave = threadIdx.x >> 6;
    int lane = threadIdx.x & 63;
    int r0 = blockIdx.x * 128 + wave * 32;
    if (r0 >= M) return;

    int rowA = lane & 15;
    int ksub = (lane >> 4) * 8;

    Frag16 a[2][4];
#pragma unroll
    for (int rt = 0; rt < 2; ++rt) {
        int row = r0 + rt * 16 + rowA;
        if (F32IN) {
            const float* xr = (const float*)Xv + (size_t)row * 128;
#pragma unroll
            for (int kt = 0; kt < 4; ++kt) {
                float4 lo = *(const float4*)(xr + kt * 32 + ksub);
                float4 hi = *(const float4*)(xr + kt * 32 + ksub + 4);
                float r[8] = {lo.x, lo.y, lo.z, lo.w, hi.x, hi.y, hi.z, hi.w};
                a[rt][kt].u = pack8(r);
            }
        } else {
            const uint4* xr = (const uint4*)Xv + (size_t)row * 16;
#pragma unroll
            for (int kt = 0; kt < 4; ++kt) a[rt][kt].u = xr[kt * 4 + (lane >> 4)];
        }
    }

    f32x4 acc[2][8];
#pragma unroll
    for (int rt = 0; rt < 2; ++rt)
#pragma unroll
        for (int nt = 0; nt < 8; ++nt) acc[rt][nt] = (f32x4){0.f, 0.f, 0.f, 0.f};

#pragma unroll
    for (int kt = 0; kt < 4; ++kt) {
#pragma unroll
        for (int nt = 0; nt < 8; ++nt) {
            Frag16 b;
            b.u = WBs[(kt * 8 + nt) * 64 + lane];
            acc[0][nt] = __builtin_amdgcn_mfma_f32_16x16x32_bf16(a[0][kt].s, b.s, acc[0][nt], 0, 0, 0);
            acc[1][nt] = __builtin_amdgcn_mfma_f32_16x16x32_bf16(a[1][kt].s, b.s, acc[1][nt], 0, 0, 0);
        }
    }

    int cbase = lane & 15;
#pragma unroll
    for (int rt = 0; rt < 2; ++rt) {
        int rbase = r0 + rt * 16 + (lane >> 4) * 4;
#pragma unroll
        for (int nt = 0; nt < 8; ++nt) {
#pragma unroll
            for (int j = 0; j < 4; ++j) {
                Y[(size_t)(rbase + j) * 128 + nt * 16 + cbase] = f2bf(acc[rt][nt][j]);
            }
        }
    }
}

// ---------------- aggregation: one wave per node, quarter-wave per neighbor row ----------------
// 4 gathers in flight per wave-iteration (16 rows/wave across groups).
__global__ __launch_bounds__(256) void aggregate_kernel(
    const ushort* __restrict__ T, const int* __restrict__ csr,
    const int* __restrict__ rowptr, const int* __restrict__ degi,
    const float* __restrict__ dis, const float* __restrict__ bias,
    ushort* __restrict__ H) {
    int node = blockIdx.x * 4 + (threadIdx.x >> 6);
    int lane = threadIdx.x & 63;
    if (node >= N_NODES) return;
    int group = lane >> 4;
    int sub   = lane & 15;

    float di = dis[node];
    int start = rowptr[node];
    int cnt = degi[node];
    const uint4* T4 = (const uint4*)T;

    float acc[8];
#pragma unroll
    for (int i = 0; i < 8; i++) acc[i] = 0.f;

    int j = group;
    for (; j + 12 < cnt; j += 16) {
        int s0 = csr[start + j];
        int s1 = csr[start + j + 4];
        int s2 = csr[start + j + 8];
        int s3 = csr[start + j + 12];
        float c0 = di * dis[s0];
        float c1 = di * dis[s1];
        float c2 = di * dis[s2];
        float c3 = di * dis[s3];
        uint4 v0 = T4[(size_t)s0 * 16 + sub];
        uint4 v1 = T4[(size_t)s1 * 16 + sub];
        uint4 v2 = T4[(size_t)s2 * 16 + sub];
        uint4 v3 = T4[(size_t)s3 * 16 + sub];
        float f0[8], f1[8], f2[8], f3[8];
        unpack8(v0, f0); unpack8(v1, f1); unpack8(v2, f2); unpack8(v3, f3);
#pragma unroll
        for (int i = 0; i < 8; i++)
            acc[i] += c0 * f0[i] + c1 * f1[i] + c2 * f2[i] + c3 * f3[i];
    }
    for (; j < cnt; j += 4) {
        int s0 = csr[start + j];
        float c0 = di * dis[s0];
        uint4 v0 = T4[(size_t)s0 * 16 + sub];
        float f0[8];
        unpack8(v0, f0);
#pragma unroll
        for (int i = 0; i < 8; i++) acc[i] += c0 * f0[i];
    }

#pragma unroll
    for (int i = 0; i < 8; i++) {
        acc[i] += __shfl_xor(acc[i], 16);
        acc[i] += __shfl_xor(acc[i], 32);
    }

    if (group == 0) {
        uint4 sv = T4[(size_t)node * 16 + sub];
        float sf[8];
        unpack8(sv, sf);
        float invdeg = di * di;
        float4 blo = ((const float4*)bias)[sub * 2];
        float4 bhi = ((const float4*)bias)[sub * 2 + 1];
        float bb[8] = {blo.x, blo.y, blo.z, blo.w, bhi.x, bhi.y, bhi.z, bhi.w};
        float r[8];
#pragma unroll
        for (int i = 0; i < 8; i++) r[i] = fmaxf(acc[i] + invdeg * sf[i] + bb[i], 0.f);
        ((uint4*)H)[(size_t)node * 16 + sub] = pack8(r);
    }
}

// ---------------- pool: chunked per-wave run-accumulation over sorted batch ----------------
__global__ __launch_bounds__(256) void pool_kernel(const ushort* __restrict__ H,
                                                   const int* __restrict__ batch,
                                                   const float* __restrict__ Wfc,
                                                   float* __restrict__ gsum) {
    int wave = threadIdx.x >> 6;
    int lane = threadIdx.x & 63;
    int wid = blockIdx.x * 4 + wave;
    const int nwaves = POOL_BLOCKS * 4;
    const int per = (N_NODES + nwaves - 1) / nwaves;
    int start = wid * per;
    int end = min(start + per, N_NODES);
    if (start >= end) return;

    const uint* H1 = (const uint*)H;
    float2 w = ((const float2*)Wfc)[lane];
    float2 acc = make_float2(0.f, 0.f);
    int gcur = batch[start];

    for (int node = start; node < end; ++node) {
        int g = batch[node];
        if (g != gcur) {
            float d = acc.x * w.x + acc.y * w.y;
#pragma unroll
            for (int off = 32; off > 0; off >>= 1) d += __shfl_down(d, off);
            if (lane == 0) atomicAdd(&gsum[gcur], d);
            acc = make_float2(0.f, 0.f);
            gcur = g;
        }
        uint v = H1[(size_t)node * 64 + lane];
        acc.x += bf2f((ushort)(v & 0xFFFF));
        acc.y += bf2f((ushort)(v >> 16));
    }
    float d = acc.x * w.x + acc.y * w.y;
#pragma unroll
    for (int off = 32; off > 0; off >>= 1) d += __shfl_down(d, off);
    if (lane == 0) atomicAdd(&gsum[gcur], d);
}

// ---------------- finalize ----------------
__global__ void finalize_kernel(const float* __restrict__ gsum, const int* __restrict__ batch,
                                const float* __restrict__ bfc, float* __restrict__ out) {
    int g = threadIdx.x;
    if (g >= N_GRAPHS) return;
    auto lb = [&](int key) {
        int lo = 0, hi = N_NODES;
        while (lo < hi) {
            int mid = (lo + hi) >> 1;
            if (batch[mid] < key) lo = mid + 1; else hi = mid;
        }
        return lo;
    };
    int a = lb(g), b = lb(g + 1);
    float cnt = (float)(b - a);
    out[g] = gsum[g] / fmaxf(cnt, 1.0f) + bfc[0];
}

// ---------------- launcher ----------------
extern "C" void kernel_launch(void* const* d_in, const int* in_sizes, int n_in,
                              void* d_out, int out_size, void* d_ws, size_t ws_size,
                              hipStream_t stream) {
    const float* x    = (const float*)d_in[0];
    const int*   eidx = (const int*)d_in[1];
    const int*   batch= (const int*)d_in[2];
    const float* W1   = (const float*)d_in[3];
    const float* b1   = (const float*)d_in[4];
    const float* W2   = (const float*)d_in[5];
    const float* b2   = (const float*)d_in[6];
    const float* Wfc  = (const float*)d_in[7];
    const float* bfc  = (const float*)d_in[8];
    float* out = (float*)d_out;

    const int* src = eidx;
    const int* dst = eidx + N_EDGES;

    size_t off = 0;
    char* base = (char*)d_ws;
    auto alloc = [&](size_t bytes) -> void* {
        void* p = base + off;
        off += (bytes + 255) & ~(size_t)255;
        return p;
    };
    // zeroed region first: bcnt, bfill, gsum
    int*    bcnt   = (int*)alloc(NBUCK * 4);
    int*    bfill  = (int*)alloc(NBUCK * 4);
    float*  gsum   = (float*)alloc(N_GRAPHS * 4);
    size_t zero_bytes = off;
    ushort* A      = (ushort*)alloc((size_t)N_NODES * HID * 2);
    ushort* B      = (ushort*)alloc((size_t)N_NODES * HID * 2);
    int*    degi   = (int*)alloc(N_NODES * 4);
    int*    rowptr = (int*)alloc(N_NODES * 4);
    float*  dis    = (float*)alloc(N_NODES * 4);
    int*    csr    = (int*)alloc(N_EDGES * 4);
    uint*   bucketed = (uint*)alloc((size_t)N_EDGES * 4);
    int*    bbase  = (int*)alloc((NBUCK + 1) * 4);
    uint4*  WB1    = (uint4*)alloc(2048 * 16);
    uint4*  WB2    = (uint4*)alloc(2048 * 16);

    int zn = (int)(zero_bytes / 4);
    zero_kernel<<<(zn + 255) / 256, 256, 0, stream>>>((int*)base, zn);

    // bucketed CSR build
    hist_kernel<<<NBLK_A, 256, 0, stream>>>(dst, bcnt);
    bscan_kernel<<<1, 256, 0, stream>>>(bcnt, bbase);
    bucket_scatter_kernel<<<NBLK_A, 256, 0, stream>>>(src, dst, bbase, bfill, bucketed);
    bucket_csr_kernel<<<NBUCK, 256, 0, stream>>>(bucketed, bbase, degi, rowptr, csr);
    dis_kernel<<<(N_NODES + 255) / 256, 256, 0, stream>>>(degi, dis);

    // W fragment pre-pack
    prep_wfrag<<<8, 256, 0, stream>>>(W1, WB1);
    prep_wfrag<<<8, 256, 0, stream>>>(W2, WB2);

    int gemm_grid = (N_NODES + 127) / 128;
    int agg_grid  = (N_NODES + 3) / 4;

    // layer 1
    mgemm_kernel<true><<<gemm_grid, 256, 0, stream>>>(x, WB1, A, N_NODES);
    aggregate_kernel<<<agg_grid, 256, 0, stream>>>(A, csr, rowptr, degi, dis, b1, B);
    // layer 2
    mgemm_kernel<false><<<gemm_grid, 256, 0, stream>>>(B, WB2, A, N_NODES);
    aggregate_kernel<<<agg_grid, 256, 0, stream>>>(A, csr, rowptr, degi, dis, b2, B);

    // pool + fc
    pool_kernel<<<POOL_BLOCKS, 256, 0, stream>>>(B, batch, Wfc, gsum);
    finalize_kernel<<<1, 256, 0, stream>>>(gsum, batch, bfc, out);
}

// Round 6
// 261.919 us; speedup vs baseline: 3.8078x; 1.0360x over previous
//
#include <hip/hip_runtime.h>

#define N_NODES 100000
#define N_EDGES 1600000
#define HID 128
#define N_GRAPHS 256
#define POOL_BLOCKS 512

#define BSHIFT 9
#define BSIZE 512
#define NBUCK ((N_NODES + BSIZE - 1) / BSIZE)   // 196
#define EPB 8192
#define NBLK_A ((N_EDGES + EPB - 1) / EPB)      // 196

typedef unsigned int uint;
typedef unsigned short ushort;
typedef short short8 __attribute__((ext_vector_type(8)));
typedef float f32x4 __attribute__((ext_vector_type(4)));

__device__ __forceinline__ float bf2f(ushort u) {
    return __uint_as_float(((uint)u) << 16);
}
__device__ __forceinline__ ushort f2bf(float f) {
    uint u = __float_as_uint(f);
    u += 0x7FFFu + ((u >> 16) & 1u);   // round-to-nearest-even
    return (ushort)(u >> 16);
}
__device__ __forceinline__ uint4 pack8(const float* r) {
    uint4 o;
    o.x = (uint)f2bf(r[0]) | ((uint)f2bf(r[1]) << 16);
    o.y = (uint)f2bf(r[2]) | ((uint)f2bf(r[3]) << 16);
    o.z = (uint)f2bf(r[4]) | ((uint)f2bf(r[5]) << 16);
    o.w = (uint)f2bf(r[6]) | ((uint)f2bf(r[7]) << 16);
    return o;
}
// accumulate 8 bf16 (packed in uint4) into 8 fp32: lo = u<<16, hi = u&0xFFFF0000
__device__ __forceinline__ void acc8(uint4 v, float* a) {
    a[0] += __uint_as_float(v.x << 16);
    a[1] += __uint_as_float(v.x & 0xFFFF0000u);
    a[2] += __uint_as_float(v.y << 16);
    a[3] += __uint_as_float(v.y & 0xFFFF0000u);
    a[4] += __uint_as_float(v.z << 16);
    a[5] += __uint_as_float(v.z & 0xFFFF0000u);
    a[6] += __uint_as_float(v.w << 16);
    a[7] += __uint_as_float(v.w & 0xFFFF0000u);
}

union Frag16 {
    uint4 u;
    short8 s;
    ushort h[8];
};

// ---------------- zero ----------------
__global__ void zero_kernel(int* __restrict__ p, int n) {
    int i = blockIdx.x * blockDim.x + threadIdx.x;
    if (i < n) p[i] = 0;
}

// ---------------- bucketed CSR build ----------------
// Pass 1: per-block LDS histogram + per-(block,bucket) reservation
__global__ __launch_bounds__(256) void hist_reserve_kernel(const int* __restrict__ dst,
                                                           int* __restrict__ bfill,
                                                           int* __restrict__ rbg) {
    __shared__ int h[NBUCK];
    for (int t = threadIdx.x; t < NBUCK; t += 256) h[t] = 0;
    __syncthreads();
    int base = blockIdx.x * EPB;
#pragma unroll 4
    for (int it = 0; it < EPB / 256; ++it) {
        int e = base + it * 256 + threadIdx.x;
        if (e < N_EDGES) atomicAdd(&h[dst[e] >> BSHIFT], 1);
    }
    __syncthreads();
    for (int t = threadIdx.x; t < NBUCK; t += 256) {
        int rb = h[t] ? atomicAdd(&bfill[t], h[t]) : 0;
        rbg[blockIdx.x * NBUCK + t] = rb;
    }
}

// Pass 2: exclusive scan of bucket totals (1 block)
__global__ __launch_bounds__(256) void bscan_kernel(const int* __restrict__ bfill,
                                                    int* __restrict__ bbase) {
    __shared__ int s[256];
    int t = threadIdx.x;
    int v = (t < NBUCK) ? bfill[t] : 0;
    s[t] = v;
    __syncthreads();
    for (int off = 1; off < 256; off <<= 1) {
        int a = (t >= off) ? s[t - off] : 0;
        __syncthreads();
        s[t] += a;
        __syncthreads();
    }
    if (t < NBUCK) bbase[t] = s[t] - v;
    if (t == NBUCK - 1) bbase[NBUCK] = s[t];
}

// Pass 3: scatter packed edges into bucket regions (bases precomputed in pass 1)
__global__ __launch_bounds__(256) void bucket_scatter_kernel(const int* __restrict__ src,
                                                             const int* __restrict__ dst,
                                                             const int* __restrict__ bbase,
                                                             const int* __restrict__ rbg,
                                                             uint* __restrict__ bucketed) {
    __shared__ int h[NBUCK];
    __shared__ int rb[NBUCK];
    for (int t = threadIdx.x; t < NBUCK; t += 256) {
        h[t] = 0;
        rb[t] = rbg[blockIdx.x * NBUCK + t] + bbase[t];
    }
    __syncthreads();
    int base = blockIdx.x * EPB;
#pragma unroll 4
    for (int it = 0; it < EPB / 256; ++it) {
        int e = base + it * 256 + threadIdx.x;
        if (e < N_EDGES) {
            int d = dst[e];
            int b = d >> BSHIFT;
            int pos = rb[b] + atomicAdd(&h[b], 1);
            bucketed[pos] = (uint)src[e] | ((uint)(d & (BSIZE - 1)) << 17);
        }
    }
}

// Pass 4: one block per bucket -> local count/scan/scatter; contiguous global writes
__global__ __launch_bounds__(256) void bucket_csr_kernel(const uint* __restrict__ bucketed,
                                                         const int* __restrict__ bbase,
                                                         int* __restrict__ degi,
                                                         int* __restrict__ rowptr,
                                                         int* __restrict__ csr) {
    int b = blockIdx.x;
    int beg = bbase[b], end = bbase[b + 1];
    int ne = end - beg;
    __shared__ int cnt[BSIZE];
    __shared__ int fl[BSIZE];
    __shared__ int ex[BSIZE];
    __shared__ int ps[256];
    int t = threadIdx.x;
    cnt[t] = 0; cnt[t + 256] = 0;
    fl[t] = 0;  fl[t + 256] = 0;
    __syncthreads();
    for (int i = t; i < ne; i += 256) atomicAdd(&cnt[bucketed[beg + i] >> 17], 1);
    __syncthreads();
    int v0 = cnt[2 * t], v1 = cnt[2 * t + 1];
    int s = v0 + v1;
    ps[t] = s;
    __syncthreads();
    for (int off = 1; off < 256; off <<= 1) {
        int a = (t >= off) ? ps[t - off] : 0;
        __syncthreads();
        ps[t] += a;
        __syncthreads();
    }
    int e0 = ps[t] - s;
    ex[2 * t] = e0;
    ex[2 * t + 1] = e0 + v0;
    int g = b * BSIZE + 2 * t;
    if (g < N_NODES) { degi[g] = v0; rowptr[g] = beg + e0; }
    if (g + 1 < N_NODES) { degi[g + 1] = v1; rowptr[g + 1] = beg + e0 + v0; }
    __syncthreads();
    for (int i = t; i < ne; i += 256) {
        uint u = bucketed[beg + i];
        int dl = u >> 17;
        int p = ex[dl] + atomicAdd(&fl[dl], 1);
        csr[beg + p] = (int)(u & 0x1FFFF);
    }
}

__global__ void dis_kernel(const int* __restrict__ degi, float* __restrict__ dis) {
    int i = blockIdx.x * blockDim.x + threadIdx.x;
    if (i < N_NODES) dis[i] = rsqrtf(1.0f + (float)degi[i]);
}

// ---------------- W -> B-fragment pre-pack ----------------
__global__ void prep_wfrag(const float* __restrict__ W, uint4* __restrict__ WB) {
    int t = blockIdx.x * 256 + threadIdx.x;
    if (t >= 2048) return;
    int lane = t & 63;
    int nt = (t >> 6) & 7;
    int kt = t >> 9;
    int kbase = kt * 32 + (lane >> 4) * 8;
    int col = nt * 16 + (lane & 15);
    float r[8];
#pragma unroll
    for (int j = 0; j < 8; j++) r[j] = W[(size_t)(kbase + j) * 128 + col];
    WB[t] = pack8(r);
}

// ---------------- MFMA GEMM: Y_bf16[M,128] = (X[M,128] @ W) * dis[row] ----------------
template <bool F32IN>
__global__ __launch_bounds__(256) void mgemm_kernel(const void* __restrict__ Xv,
                                                    const uint4* __restrict__ WB,
                                                    const float* __restrict__ dis,
                                                    ushort* __restrict__ Y, int M) {
    __shared__ uint4 WBs[2048];
#pragma unroll
    for (int i = 0; i < 8; i++) WBs[i * 256 + threadIdx.x] = WB[i * 256 + threadIdx.x];
    __syncthreads();

    int wave = threadIdx.x >> 6;
    int lane = threadIdx.x & 63;
    int r0 = blockIdx.x * 128 + wave * 32;
    if (r0 >= M) return;

    int rowA = lane & 15;
    int ksub = (lane >> 4) * 8;

    Frag16 a[2][4];
#pragma unroll
    for (int rt = 0; rt < 2; ++rt) {
        int row = r0 + rt * 16 + rowA;
        if (F32IN) {
            const float* xr = (const float*)Xv + (size_t)row * 128;
#pragma unroll
            for (int kt = 0; kt < 4; ++kt) {
                float4 lo = *(const float4*)(xr + kt * 32 + ksub);
                float4 hi = *(const float4*)(xr + kt * 32 + ksub + 4);
                float r[8] = {lo.x, lo.y, lo.z, lo.w, hi.x, hi.y, hi.z, hi.w};
                a[rt][kt].u = pack8(r);
            }
        } else {
            const uint4* xr = (const uint4*)Xv + (size_t)row * 16;
#pragma unroll
            for (int kt = 0; kt < 4; ++kt) a[rt][kt].u = xr[kt * 4 + (lane >> 4)];
        }
    }

    f32x4 acc[2][8];
#pragma unroll
    for (int rt = 0; rt < 2; ++rt)
#pragma unroll
        for (int nt = 0; nt < 8; ++nt) acc[rt][nt] = (f32x4){0.f, 0.f, 0.f, 0.f};

#pragma unroll
    for (int kt = 0; kt < 4; ++kt) {
#pragma unroll
        for (int nt = 0; nt < 8; ++nt) {
            Frag16 b;
            b.u = WBs[(kt * 8 + nt) * 64 + lane];
            acc[0][nt] = __builtin_amdgcn_mfma_f32_16x16x32_bf16(a[0][kt].s, b.s, acc[0][nt], 0, 0, 0);
            acc[1][nt] = __builtin_amdgcn_mfma_f32_16x16x32_bf16(a[1][kt].s, b.s, acc[1][nt], 0, 0, 0);
        }
    }

    // C/D layout: col = lane&15, row = (lane>>4)*4 + reg; scale by dis[row]
    int cbase = lane & 15;
#pragma unroll
    for (int rt = 0; rt < 2; ++rt) {
        int rbase = r0 + rt * 16 + (lane >> 4) * 4;
        float d0 = dis[rbase + 0], d1 = dis[rbase + 1];
        float d2 = dis[rbase + 2], d3 = dis[rbase + 3];
#pragma unroll
        for (int nt = 0; nt < 8; ++nt) {
            Y[(size_t)(rbase + 0) * 128 + nt * 16 + cbase] = f2bf(acc[rt][nt][0] * d0);
            Y[(size_t)(rbase + 1) * 128 + nt * 16 + cbase] = f2bf(acc[rt][nt][1] * d1);
            Y[(size_t)(rbase + 2) * 128 + nt * 16 + cbase] = f2bf(acc[rt][nt][2] * d2);
            Y[(size_t)(rbase + 3) * 128 + nt * 16 + cbase] = f2bf(acc[rt][nt][3] * d3);
        }
    }
}

// ---------------- aggregation ----------------
// T holds T' = (X@W)*dis[src]. agg[dst] = relu(dis[dst]*(sum_nbr T'[s] + T'[dst]) + b).
// One wave per node, quarter-wave (16 lanes) per neighbor row, 4 rows in flight/group.
__global__ __launch_bounds__(256) void aggregate_kernel(
    const ushort* __restrict__ T, const int* __restrict__ csr,
    const int* __restrict__ rowptr, const int* __restrict__ degi,
    const float* __restrict__ dis, const float* __restrict__ bias,
    ushort* __restrict__ H) {
    int node = blockIdx.x * 4 + (threadIdx.x >> 6);
    int lane = threadIdx.x & 63;
    if (node >= N_NODES) return;
    int group = lane >> 4;
    int sub   = lane & 15;

    int start = rowptr[node];
    int cnt = degi[node];
    const uint4* T4 = (const uint4*)T;

    float acc[8];
#pragma unroll
    for (int i = 0; i < 8; i++) acc[i] = 0.f;

    int j = group;
    for (; j + 12 < cnt; j += 16) {
        int s0 = csr[start + j];
        int s1 = csr[start + j + 4];
        int s2 = csr[start + j + 8];
        int s3 = csr[start + j + 12];
        uint4 v0 = T4[(size_t)s0 * 16 + sub];
        uint4 v1 = T4[(size_t)s1 * 16 + sub];
        uint4 v2 = T4[(size_t)s2 * 16 + sub];
        uint4 v3 = T4[(size_t)s3 * 16 + sub];
        acc8(v0, acc); acc8(v1, acc); acc8(v2, acc); acc8(v3, acc);
    }
    for (; j < cnt; j += 4) {
        int s0 = csr[start + j];
        uint4 v0 = T4[(size_t)s0 * 16 + sub];
        acc8(v0, acc);
    }

#pragma unroll
    for (int i = 0; i < 8; i++) {
        acc[i] += __shfl_xor(acc[i], 16);
        acc[i] += __shfl_xor(acc[i], 32);
    }

    if (group == 0) {
        // self term (weight 1), then scale by dis[node], bias, relu
        uint4 sv = T4[(size_t)node * 16 + sub];
        acc8(sv, acc);
        float di = dis[node];
        float4 blo = ((const float4*)bias)[sub * 2];
        float4 bhi = ((const float4*)bias)[sub * 2 + 1];
        float bb[8] = {blo.x, blo.y, blo.z, blo.w, bhi.x, bhi.y, bhi.z, bhi.w};
        float r[8];
#pragma unroll
        for (int i = 0; i < 8; i++) r[i] = fmaxf(di * acc[i] + bb[i], 0.f);
        ((uint4*)H)[(size_t)node * 16 + sub] = pack8(r);
    }
}

// ---------------- pool: chunked per-wave run-accumulation over sorted batch ----------------
__global__ __launch_bounds__(256) void pool_kernel(const ushort* __restrict__ H,
                                                   const int* __restrict__ batch,
                                                   const float* __restrict__ Wfc,
                                                   float* __restrict__ gsum) {
    int wave = threadIdx.x >> 6;
    int lane = threadIdx.x & 63;
    int wid = blockIdx.x * 4 + wave;
    const int nwaves = POOL_BLOCKS * 4;
    const int per = (N_NODES + nwaves - 1) / nwaves;
    int start = wid * per;
    int end = min(start + per, N_NODES);
    if (start >= end) return;

    const uint* H1 = (const uint*)H;
    float2 w = ((const float2*)Wfc)[lane];
    float2 acc = make_float2(0.f, 0.f);
    int gcur = batch[start];

    for (int node = start; node < end; ++node) {
        int g = batch[node];
        if (g != gcur) {
            float d = acc.x * w.x + acc.y * w.y;
#pragma unroll
            for (int off = 32; off > 0; off >>= 1) d += __shfl_down(d, off);
            if (lane == 0) atomicAdd(&gsum[gcur], d);
            acc = make_float2(0.f, 0.f);
            gcur = g;
        }
        uint v = H1[(size_t)node * 64 + lane];
        acc.x += bf2f((ushort)(v & 0xFFFF));
        acc.y += bf2f((ushort)(v >> 16));
    }
    float d = acc.x * w.x + acc.y * w.y;
#pragma unroll
    for (int off = 32; off > 0; off >>= 1) d += __shfl_down(d, off);
    if (lane == 0) atomicAdd(&gsum[gcur], d);
}

// ---------------- finalize ----------------
__global__ void finalize_kernel(const float* __restrict__ gsum, const int* __restrict__ batch,
                                const float* __restrict__ bfc, float* __restrict__ out) {
    int g = threadIdx.x;
    if (g >= N_GRAPHS) return;
    auto lb = [&](int key) {
        int lo = 0, hi = N_NODES;
        while (lo < hi) {
            int mid = (lo + hi) >> 1;
            if (batch[mid] < key) lo = mid + 1; else hi = mid;
        }
        return lo;
    };
    int a = lb(g), b = lb(g + 1);
    float cnt = (float)(b - a);
    out[g] = gsum[g] / fmaxf(cnt, 1.0f) + bfc[0];
}

// ---------------- launcher ----------------
extern "C" void kernel_launch(void* const* d_in, const int* in_sizes, int n_in,
                              void* d_out, int out_size, void* d_ws, size_t ws_size,
                              hipStream_t stream) {
    const float* x    = (const float*)d_in[0];
    const int*   eidx = (const int*)d_in[1];
    const int*   batch= (const int*)d_in[2];
    const float* W1   = (const float*)d_in[3];
    const float* b1   = (const float*)d_in[4];
    const float* W2   = (const float*)d_in[5];
    const float* b2   = (const float*)d_in[6];
    const float* Wfc  = (const float*)d_in[7];
    const float* bfc  = (const float*)d_in[8];
    float* out = (float*)d_out;

    const int* src = eidx;
    const int* dst = eidx + N_EDGES;

    size_t off = 0;
    char* base = (char*)d_ws;
    auto alloc = [&](size_t bytes) -> void* {
        void* p = base + off;
        off += (bytes + 255) & ~(size_t)255;
        return p;
    };
    // zeroed region first: bfill, gsum
    int*    bfill  = (int*)alloc(NBUCK * 4);
    float*  gsum   = (float*)alloc(N_GRAPHS * 4);
    size_t zero_bytes = off;
    ushort* A      = (ushort*)alloc((size_t)N_NODES * HID * 2);
    ushort* B      = (ushort*)alloc((size_t)N_NODES * HID * 2);
    int*    degi   = (int*)alloc(N_NODES * 4);
    int*    rowptr = (int*)alloc(N_NODES * 4);
    float*  dis    = (float*)alloc(N_NODES * 4);
    int*    csr    = (int*)alloc(N_EDGES * 4);
    uint*   bucketed = (uint*)alloc((size_t)N_EDGES * 4);
    int*    bbase  = (int*)alloc((NBUCK + 1) * 4);
    int*    rbg    = (int*)alloc((size_t)NBLK_A * NBUCK * 4);
    uint4*  WB1    = (uint4*)alloc(2048 * 16);
    uint4*  WB2    = (uint4*)alloc(2048 * 16);

    int zn = (int)(zero_bytes / 4);
    zero_kernel<<<(zn + 255) / 256, 256, 0, stream>>>((int*)base, zn);

    // bucketed CSR build
    hist_reserve_kernel<<<NBLK_A, 256, 0, stream>>>(dst, bfill, rbg);
    bscan_kernel<<<1, 256, 0, stream>>>(bfill, bbase);
    bucket_scatter_kernel<<<NBLK_A, 256, 0, stream>>>(src, dst, bbase, rbg, bucketed);
    bucket_csr_kernel<<<NBUCK, 256, 0, stream>>>(bucketed, bbase, degi, rowptr, csr);
    dis_kernel<<<(N_NODES + 255) / 256, 256, 0, stream>>>(degi, dis);

    // W fragment pre-pack
    prep_wfrag<<<8, 256, 0, stream>>>(W1, WB1);
    prep_wfrag<<<8, 256, 0, stream>>>(W2, WB2);

    int gemm_grid = (N_NODES + 127) / 128;
    int agg_grid  = (N_NODES + 3) / 4;

    // layer 1
    mgemm_kernel<true><<<gemm_grid, 256, 0, stream>>>(x, WB1, dis, A, N_NODES);
    aggregate_kernel<<<agg_grid, 256, 0, stream>>>(A, csr, rowptr, degi, dis, b1, B);
    // layer 2
    mgemm_kernel<false><<<gemm_grid, 256, 0, stream>>>(B, WB2, dis, A, N_NODES);
    aggregate_kernel<<<agg_grid, 256, 0, stream>>>(A, csr, rowptr, degi, dis, b2, B);

    // pool + fc
    pool_kernel<<<POOL_BLOCKS, 256, 0, stream>>>(B, batch, Wfc, gsum);
    finalize_kernel<<<1, 256, 0, stream>>>(gsum, batch, bfc, out);
}